// Round 3
// baseline (2611.289 us; speedup 1.0000x reference)
//
#include <hip/hip_runtime.h>
#include <cstddef>

typedef short bfx8 __attribute__((ext_vector_type(8)));
typedef float f32x4 __attribute__((ext_vector_type(4)));

#define BATCH   4096
#define DXP     32
#define NSTEPS  100
#define NE      8       // batch elements per block (MFMA M rows 8-15 are padding)
#define NWAVE   8       // waves per block
#define NJT     2       // j-tiles per wave in 256-wide hidden layers
#define KS      264     // A-buffer row stride in bf16 elems
#define XS      100     // xsF/gbuf row stride in floats
#define PIO2F   1.57079632679489662f

__device__ __forceinline__ unsigned short f2bf(float v){
    unsigned u = __float_as_uint(v);
    u += 0x7FFFu + ((u >> 16) & 1u);          // RNE
    return (unsigned short)(u >> 16);
}
__device__ __forceinline__ float bf2f(unsigned short h){
    return __uint_as_float(((unsigned)h) << 16);
}

// =====================================================================
// Prep: [T][K][N] fp32 -> transposed split-bf16 hi/lo [T][N][K].
// 32x32 LDS-tiled transpose, coalesced both sides. K,N multiples of 32.
// grid (N/32, K/32, T), block 256 (32x8).
// =====================================================================
__global__ __launch_bounds__(256)
void prep_split_tile(const float* __restrict__ in,
                     short* __restrict__ oh, short* __restrict__ ol,
                     int K, int N)
{
    __shared__ float tile[32][33];
    const int t  = blockIdx.z;
    const int n0 = blockIdx.x * 32, k0 = blockIdx.y * 32;
    const int tx = threadIdx.x & 31, ty = threadIdx.x >> 5;   // 32 x 8
    const float* src = in + ((size_t)t*K + k0)*N + n0;
    #pragma unroll
    for (int i = 0; i < 4; ++i)
        tile[ty + i*8][tx] = src[(size_t)(ty + i*8)*N + tx];
    __syncthreads();
    short* dh = oh + ((size_t)t*N + n0)*K + k0;
    short* dl = ol + ((size_t)t*N + n0)*K + k0;
    #pragma unroll
    for (int i = 0; i < 4; ++i) {
        const int nn = ty + i*8;
        const float v = tile[tx][nn];          // [k=tx][n=nn]
        const unsigned short h = f2bf(v);
        dh[(size_t)nn*K + tx] = (short)h;
        dl[(size_t)nn*K + tx] = (short)f2bf(v - bf2f(h));
    }
}

// =====================================================================
// MFMA hidden layer: 16m x 256j, K = KC*32, tanh, split-bf16 out.
// A from LDS [m][k] stride KS; B from GLOBAL transposed [n][k] hi/lo.
// Wave w owns j-tiles w*NJT .. w*NJT+NJT-1.
// =====================================================================
template<int KC>
__device__ __forceinline__ void layer_hidden(
    const short* __restrict__ Wh, const short* __restrict__ Wl,
    const float* __restrict__ bias,
    const short* __restrict__ inH, const short* __restrict__ inL,
    short* __restrict__ outH, short* __restrict__ outL,
    int lane, int wid)
{
    const int m = lane & 15, q = lane >> 4;
    const int K = KC * 32;

    const short* bph[NJT]; const short* bpl[NJT];
    #pragma unroll
    for (int jj = 0; jj < NJT; ++jj) {
        const int cj = (wid*NJT + jj)*16 + m;
        bph[jj] = Wh + ((size_t)cj * K + q*8);
        bpl[jj] = Wl + ((size_t)cj * K + q*8);
    }
    f32x4 acc[NJT];
    #pragma unroll
    for (int jj = 0; jj < NJT; ++jj) acc[jj] = (f32x4){0.f,0.f,0.f,0.f};

    bfx8 bh[NJT], bl[NJT];
    #pragma unroll
    for (int jj = 0; jj < NJT; ++jj) { bh[jj] = *(const bfx8*)bph[jj]; bl[jj] = *(const bfx8*)bpl[jj]; }

    __syncthreads();   // in-buffer written; out-buffer's prior readers done

    const short* aph = inH + m*KS + q*8;
    const short* apl = inL + m*KS + q*8;

    #pragma unroll
    for (int kc = 0; kc < KC; ++kc) {
        const bfx8 ah = *(const bfx8*)(aph + kc*32);
        const bfx8 al = *(const bfx8*)(apl + kc*32);
        bfx8 nh[NJT], nl[NJT];
        if (kc + 1 < KC) {
            #pragma unroll
            for (int jj = 0; jj < NJT; ++jj) {
                nh[jj] = *(const bfx8*)(bph[jj] + (kc+1)*32);
                nl[jj] = *(const bfx8*)(bpl[jj] + (kc+1)*32);
            }
        }
        #pragma unroll
        for (int jj = 0; jj < NJT; ++jj) {
            acc[jj] = __builtin_amdgcn_mfma_f32_16x16x32_bf16(ah, bh[jj], acc[jj], 0, 0, 0);
            acc[jj] = __builtin_amdgcn_mfma_f32_16x16x32_bf16(al, bh[jj], acc[jj], 0, 0, 0);
            acc[jj] = __builtin_amdgcn_mfma_f32_16x16x32_bf16(ah, bl[jj], acc[jj], 0, 0, 0);
        }
        if (kc + 1 < KC) {
            #pragma unroll
            for (int jj = 0; jj < NJT; ++jj) { bh[jj] = nh[jj]; bl[jj] = nl[jj]; }
        }
    }
    // epilogue: C row = batch elem (q*4+r), col = j (m)
    #pragma unroll
    for (int jj = 0; jj < NJT; ++jj) {
        const int cj = (wid*NJT + jj)*16 + m;
        const float bv = bias[cj];
        #pragma unroll
        for (int r = 0; r < 4; ++r) {
            const float v = tanhf(acc[jj][r] + bv);
            const unsigned short h = f2bf(v);
            const int row = q*4 + r;
            outH[row*KS + cj] = (short)h;
            outL[row*KS + cj] = (short)f2bf(v - bf2f(h));
        }
    }
}

// =====================================================================
// pMLP layer2 fused with pW3 dot (K=256).
// =====================================================================
__device__ __forceinline__ void p_l2_dot(
    const short* __restrict__ Wh, const short* __restrict__ Wl,
    const float* __restrict__ pb2, const float* __restrict__ pW3,
    const short* __restrict__ inH, const short* __restrict__ inL,
    float* __restrict__ sPpart, int lane, int wid)
{
    const int m = lane & 15, q = lane >> 4;

    const short* bph[NJT]; const short* bpl[NJT];
    #pragma unroll
    for (int jj = 0; jj < NJT; ++jj) {
        const int cj = (wid*NJT + jj)*16 + m;
        bph[jj] = Wh + ((size_t)cj * 256 + q*8);
        bpl[jj] = Wl + ((size_t)cj * 256 + q*8);
    }
    f32x4 acc[NJT];
    #pragma unroll
    for (int jj = 0; jj < NJT; ++jj) acc[jj] = (f32x4){0.f,0.f,0.f,0.f};

    __syncthreads();

    const short* aph = inH + m*KS + q*8;
    const short* apl = inL + m*KS + q*8;

    #pragma unroll
    for (int kc = 0; kc < 8; ++kc) {
        const bfx8 ah = *(const bfx8*)(aph + kc*32);
        const bfx8 al = *(const bfx8*)(apl + kc*32);
        #pragma unroll
        for (int jj = 0; jj < NJT; ++jj) {
            const bfx8 bh = *(const bfx8*)(bph[jj] + kc*32);
            const bfx8 bl = *(const bfx8*)(bpl[jj] + kc*32);
            acc[jj] = __builtin_amdgcn_mfma_f32_16x16x32_bf16(ah, bh, acc[jj], 0, 0, 0);
            acc[jj] = __builtin_amdgcn_mfma_f32_16x16x32_bf16(al, bh, acc[jj], 0, 0, 0);
            acc[jj] = __builtin_amdgcn_mfma_f32_16x16x32_bf16(ah, bl, acc[jj], 0, 0, 0);
        }
    }
    float ps[4] = {0.f, 0.f, 0.f, 0.f};
    #pragma unroll
    for (int jj = 0; jj < NJT; ++jj) {
        const int cj = (wid*NJT + jj)*16 + m;
        const float bv = pb2[cj];
        const float w3 = pW3[cj];
        #pragma unroll
        for (int r = 0; r < 4; ++r)
            ps[r] += tanhf(acc[jj][r] + bv) * w3;
    }
    #pragma unroll
    for (int mask = 1; mask <= 8; mask <<= 1) {
        #pragma unroll
        for (int r = 0; r < 4; ++r) ps[r] += __shfl_xor(ps[r], mask);
    }
    if (m == 0) {
        #pragma unroll
        for (int r = 0; r < 4; ++r) sPpart[wid*16 + q*4 + r] = ps[r];
    }
}

// =====================================================================
// Layer 3: 16m x 96o, K=256, no act, fp32 out gbuf [e][o] stride XS.
// 6 j-tiles over 8 waves (waves 6,7 idle past the barrier).
// =====================================================================
__device__ __forceinline__ void layer_out(
    const short* __restrict__ Wh, const short* __restrict__ Wl,
    const float* __restrict__ bias,
    const short* __restrict__ inH, const short* __restrict__ inL,
    float* __restrict__ gbuf, int lane, int wid)
{
    const int m = lane & 15, q = lane >> 4;
    __syncthreads();
    const short* aph = inH + m*KS + q*8;
    const short* apl = inL + m*KS + q*8;
    for (int jt = wid; jt < 6; jt += NWAVE) {
        const int cj = jt*16 + m;
        const short* bph = Wh + ((size_t)cj * 256 + q*8);
        const short* bpl = Wl + ((size_t)cj * 256 + q*8);
        f32x4 acc = (f32x4){0.f,0.f,0.f,0.f};
        #pragma unroll
        for (int kc = 0; kc < 8; ++kc) {
            const bfx8 ah = *(const bfx8*)(aph + kc*32);
            const bfx8 al = *(const bfx8*)(apl + kc*32);
            const bfx8 bh = *(const bfx8*)(bph + kc*32);
            const bfx8 bl = *(const bfx8*)(bpl + kc*32);
            acc = __builtin_amdgcn_mfma_f32_16x16x32_bf16(ah, bh, acc, 0, 0, 0);
            acc = __builtin_amdgcn_mfma_f32_16x16x32_bf16(al, bh, acc, 0, 0, 0);
            acc = __builtin_amdgcn_mfma_f32_16x16x32_bf16(ah, bl, acc, 0, 0, 0);
        }
        if (q < 2) {                      // only batch rows 0-7 exist
            const float bv = bias[cj];
            #pragma unroll
            for (int r = 0; r < 4; ++r)
                gbuf[(q*4 + r)*XS + cj] = acc[r] + bv;
        }
    }
}

// =====================================================================
// Particle / SDE update: 1 thread = 1 particle (tid < 256).
// fp32 exact, contract off. Writes new x to xsF and split-bf16 A buf.
// =====================================================================
__device__ __forceinline__ void particles_step2(
    int t, int b0, const float* __restrict__ dBt,
    float s2d, float sqdt,
    float* __restrict__ xsF, const float* __restrict__ gbuf,
    short* __restrict__ xH, short* __restrict__ xL,
    float* __restrict__ sP, float* __restrict__ sRun, float* __restrict__ sRel,
    int tid)
{
#pragma clang fp contract(off)
    const int e = tid >> 5;          // 0..7
    const int p = tid & 31;          // particle
    const int b = b0 + e;
    const float runf = sRun[e];

    const float2 db = *(const float2*)(dBt + (((size_t)t*BATCH + b)*DXP + p)*2);
    const float db0 = db.x * sqdt;
    const float db1 = db.y * sqdt;
    const float dp0 = s2d * db0;
    const float dp1 = s2d * db1;
    const float X = xsF[e*XS + 3*p + 0];
    const float Y = xsF[e*XS + 3*p + 1];
    const float Z = xsF[e*XS + 3*p + 2];
    const float zc = fminf(fmaxf(Z, -0.999999f), 0.999999f);
    const float theta = acosf(zc);
    const float phi = atan2f(Y, X);
    const float aa = theta - PIO2F;
    const float ca = cosf(aa), sa = sinf(aa);
    const float cp = cosf(phi), sp = sinf(phi);
    const float th = dp0 + PIO2F;
    const float st = sinf(th);
    const float e0v = st * cosf(dp1) - 1.0f;
    const float e1v = st * sinf(dp1);
    const float e2v = cosf(th);
    const float d0 = cp*ca*e0v - sp*e1v + cp*sa*e2v;
    const float d1 = sp*ca*e0v + cp*e1v + sp*sa*e2v;
    const float d2 = -sa*e0v + ca*e2v;
    float Xn = X + runf*d0;
    float Yn = Y + runf*d1;
    float Zn = Z + runf*d2;
    Zn = (Zn < 0.f) ? -Zn : Zn;
    int   hit   = (Zn < 0.05f) ? 1 : 0;
    float psum  = Xn + Yn + Zn;
    const float g0 = gbuf[e*XS + 3*p + 0];
    const float g1 = gbuf[e*XS + 3*p + 1];
    const float g2 = gbuf[e*XS + 3*p + 2];
    const float r1 = -g0*sp + g1*cp;
    const float r2 = g0*cp*sa + g1*sp*sa + g2*ca;
    float dpsum = (-r2)*dp0 + r1*dp1;

    xsF[e*XS + 3*p + 0] = Xn;
    xsF[e*XS + 3*p + 1] = Yn;
    xsF[e*XS + 3*p + 2] = Zn;
    const float nv[3] = {Xn, Yn, Zn};
    #pragma unroll
    for (int c = 0; c < 3; ++c) {
        const unsigned short h = f2bf(nv[c]);
        xH[e*KS + 3*p + c] = (short)h;
        xL[e*KS + 3*p + c] = (short)f2bf(nv[c] - bf2f(h));
    }
    #pragma unroll
    for (int mask = 1; mask <= 16; mask <<= 1) {
        dpsum += __shfl_xor(dpsum, mask);
        psum  += __shfl_xor(psum, mask);
        hit   |= __shfl_xor(hit, mask);
    }
    if (p == 0) {
        const float pv = sP[e];
        const float rv = runf;
        const float dp = -(0.2f * pv) * 0.01f + dpsum;
        sP[e] = pv + dp * rv;
        const bool rb = rv > 0.5f;
        if (rb && hit) sRel[e] = psum / 96.0f;
        sRun[e] = (rb && !hit) ? 1.0f : 0.0f;
    }
}

__global__ __launch_bounds__(512, 4)
void sphere_mfma_kernel(
    const float* __restrict__ x0,  const float* __restrict__ dBt,
    const float* __restrict__ Dv,
    const short* __restrict__ pW1h, const short* __restrict__ pW1l, const float* __restrict__ pb1,
    const short* __restrict__ pW2h, const short* __restrict__ pW2l, const float* __restrict__ pb2,
    const float* __restrict__ pW3,  const float* __restrict__ pb3,
    const short* __restrict__ gW1h, const short* __restrict__ gW1l, const float* __restrict__ gb1,
    const short* __restrict__ gW2h, const short* __restrict__ gW2l, const float* __restrict__ gb2,
    const short* __restrict__ gW3h, const short* __restrict__ gW3l, const float* __restrict__ gb3,
    float* __restrict__ out)
{
    __shared__ short aH0[16*KS], aL0[16*KS], aH1[16*KS], aL1[16*KS];
    __shared__ float xsF[NE*XS], gbuf[NE*XS];
    __shared__ float sPpart[NWAVE*16];
    __shared__ float sP[NE], sRun[NE], sRel[NE];

    const int tid  = threadIdx.x;
    const int lane = tid & 63, wid = tid >> 6;
    const int b0   = blockIdx.x * NE;

    // zero pad rows 8-15 of layer-1 input (x region, cols 0..95 read)
    for (int i = tid; i < 8*KS; i += 512) { aH0[8*KS + i] = 0; aL0[8*KS + i] = 0; }

    // x0 -> xsF (fp32) + split-bf16 A buffer, rows 0..7
    for (int i = tid; i < NE*96; i += 512) {
        const int e = i / 96, k = i - e*96;
        const float v = x0[(size_t)b0*96 + i];
        xsF[e*XS + k] = v;
        const unsigned short h = f2bf(v);
        aH0[e*KS + k] = (short)h;
        aL0[e*KS + k] = (short)f2bf(v - bf2f(h));
    }

    // ---- p0 = pMLP(x0), layer2 fused with pW3 dot ----
    layer_hidden<3>(pW1h, pW1l, pb1, aH0, aL0, aH1, aL1, lane, wid);
    p_l2_dot(pW2h, pW2l, pb2, pW3, aH1, aL1, sPpart, lane, wid);
    __syncthreads();
    if (tid < NE) {
        float s = pb3[0];
        #pragma unroll
        for (int w = 0; w < NWAVE; ++w) s += sPpart[w*16 + tid];
        sP[tid] = s; sRun[tid] = 1.0f; sRel[tid] = 0.0f;
    }

    float s2d = 0.f;
    if (tid < 256) s2d = sqrtf(2.0f * Dv[tid & 31]);
    const float sqdt = sqrtf(0.01f);

    // ---- 100 scan steps ----
    for (int t = 0; t < NSTEPS; ++t) {
        layer_hidden<3>(gW1h + (size_t)t*24576, gW1l + (size_t)t*24576,
                        gb1 + (size_t)t*256, aH0, aL0, aH1, aL1, lane, wid);
        layer_hidden<8>(gW2h + (size_t)t*65536, gW2l + (size_t)t*65536,
                        gb2 + (size_t)t*256, aH1, aL1, aH0, aL0, lane, wid);
        layer_out(gW3h + (size_t)t*24576, gW3l + (size_t)t*24576,
                  gb3 + (size_t)t*96, aH0, aL0, gbuf, lane, wid);
        __syncthreads();
        if (tid < 256)
            particles_step2(t, b0, dBt, s2d, sqdt, xsF, gbuf, aH0, aL0,
                            sP, sRun, sRel, tid);
    }

    // ---- finalize ----
    __syncthreads();
    if (tid < 256) {
        const int e = tid >> 5, tt = tid & 31;
        const int b = b0 + e;
        float s = xsF[e*XS + 3*tt] + xsF[e*XS + 3*tt + 1] + xsF[e*XS + 3*tt + 2];
        #pragma unroll
        for (int mask = 1; mask <= 16; mask <<= 1) s += __shfl_xor(s, mask);
        if (tt == 0) {
            out[2*b] = sP[e];
            float pr = sRel[e];
            if (sRun[e] > 0.5f) pr = s / 96.0f;
            out[2*b + 1] = pr;
        }
    }
}

// =====================================================================
// ===================== FALLBACK (fp32, round-1) ======================
// Used only if ws_size is too small for the split-bf16 weights.
// =====================================================================
#define FNE 16
#define SH 20
#define SX 16

__device__ __forceinline__ void layer256_fb(
    int K, const float* __restrict__ W, const float* __restrict__ bias,
    const float* __restrict__ in_lds, int in_stride,
    float* __restrict__ out_lds, float* __restrict__ wbuf, int tid)
{
    const int jg = tid & 63;
    const int eg = tid >> 6;
    const int j0 = jg << 2;
    const int e0 = eg << 2;
    float acc[4][4];
    #pragma unroll
    for (int ee = 0; ee < 4; ++ee)
        #pragma unroll
        for (int jj = 0; jj < 4; ++jj) acc[ee][jj] = 0.f;
    const int nc = K >> 4;
    const float4* __restrict__ Wv = (const float4*)W;
    float4* wv = (float4*)wbuf;
    float4 pre[4];
    #pragma unroll
    for (int i = 0; i < 4; ++i) pre[i] = Wv[tid + i*256];
    for (int c = 0; c < nc; ++c) {
        __syncthreads();
        #pragma unroll
        for (int i = 0; i < 4; ++i) wv[tid + i*256] = pre[i];
        if (c + 1 < nc) {
            #pragma unroll
            for (int i = 0; i < 4; ++i) pre[i] = Wv[(c+1)*1024 + tid + i*256];
        }
        __syncthreads();
        const float* inb = in_lds + (c << 4) * in_stride + e0;
        #pragma unroll
        for (int kk = 0; kk < 16; ++kk) {
            const float4 a = *(const float4*)(inb + kk * in_stride);
            const float4 w = *(const float4*)(wbuf + kk*256 + j0);
            const float av[4] = {a.x, a.y, a.z, a.w};
            const float wl[4] = {w.x, w.y, w.z, w.w};
            #pragma unroll
            for (int ee = 0; ee < 4; ++ee)
                #pragma unroll
                for (int jj = 0; jj < 4; ++jj)
                    acc[ee][jj] += av[ee] * wl[jj];
        }
    }
    const float4 bb = *(const float4*)(bias + j0);
    const float bv[4] = {bb.x, bb.y, bb.z, bb.w};
    #pragma unroll
    for (int jj = 0; jj < 4; ++jj) {
        float4 v;
        v.x = tanhf(acc[0][jj] + bv[jj]);
        v.y = tanhf(acc[1][jj] + bv[jj]);
        v.z = tanhf(acc[2][jj] + bv[jj]);
        v.w = tanhf(acc[3][jj] + bv[jj]);
        *(float4*)(out_lds + (j0 + jj) * SH + e0) = v;
    }
}

__device__ __forceinline__ void layer3_fb(
    const float* __restrict__ W, const float* __restrict__ bias,
    const float* __restrict__ h2, float* __restrict__ wbuf,
    float* __restrict__ gbuf, int tid)
{
    const int og = tid & 31;
    const int eg = tid >> 5;
    const int o0 = og * 3;
    const int e0 = eg << 1;
    float acc[2][3];
    #pragma unroll
    for (int ee = 0; ee < 2; ++ee)
        #pragma unroll
        for (int oo = 0; oo < 3; ++oo) acc[ee][oo] = 0.f;
    const float2* __restrict__ Wv = (const float2*)W;
    float2* wv2 = (float2*)wbuf;
    float2 pre[3];
    #pragma unroll
    for (int i = 0; i < 3; ++i) pre[i] = Wv[tid + i*256];
    for (int c = 0; c < 16; ++c) {
        __syncthreads();
        #pragma unroll
        for (int i = 0; i < 3; ++i) wv2[tid + i*256] = pre[i];
        if (c + 1 < 16) {
            #pragma unroll
            for (int i = 0; i < 3; ++i) pre[i] = Wv[(c+1)*768 + tid + i*256];
        }
        __syncthreads();
        #pragma unroll
        for (int kk = 0; kk < 16; ++kk) {
            const float2 a = *(const float2*)(h2 + (c*16 + kk)*SH + e0);
            const float* wr = wbuf + kk*96 + o0;
            const float w0 = wr[0], w1 = wr[1], w2 = wr[2];
            acc[0][0] += a.x*w0; acc[0][1] += a.x*w1; acc[0][2] += a.x*w2;
            acc[1][0] += a.y*w0; acc[1][1] += a.y*w1; acc[1][2] += a.y*w2;
        }
    }
    __syncthreads();
    #pragma unroll
    for (int ee = 0; ee < 2; ++ee)
        #pragma unroll
        for (int oo = 0; oo < 3; ++oo)
            gbuf[(e0 + ee)*96 + o0 + oo] = acc[ee][oo] + bias[o0 + oo];
    __syncthreads();
}

__device__ __forceinline__ void particles_step_fb(
    int t, int b0, const float* __restrict__ dBt,
    float s2d0, float s2d1, float sqdt,
    float* __restrict__ xsT, const float* __restrict__ gbuf,
    float* __restrict__ sP, float* __restrict__ sRun, float* __restrict__ sRel,
    int tid)
{
#pragma clang fp contract(off)
    const int e  = tid >> 4;
    const int tt = tid & 15;
    const int b  = b0 + e;
    const float runf = sRun[e];
    float dpsum = 0.f, psum = 0.f;
    int hit = 0;
    #pragma unroll
    for (int pp = 0; pp < 2; ++pp) {
        const int p = tt + (pp << 4);
        const float s2d = pp ? s2d1 : s2d0;
        const float2 db = *(const float2*)(dBt + (((size_t)t*BATCH + b)*DXP + p)*2);
        const float db0 = db.x * sqdt;
        const float db1 = db.y * sqdt;
        const float dp0 = s2d * db0;
        const float dp1 = s2d * db1;
        const float X = xsT[(3*p + 0)*SX + e];
        const float Y = xsT[(3*p + 1)*SX + e];
        const float Z = xsT[(3*p + 2)*SX + e];
        const float zc = fminf(fmaxf(Z, -0.999999f), 0.999999f);
        const float theta = acosf(zc);
        const float phi = atan2f(Y, X);
        const float aa = theta - PIO2F;
        const float ca = cosf(aa), sa = sinf(aa);
        const float cp = cosf(phi), sp = sinf(phi);
        const float th = dp0 + PIO2F;
        const float st = sinf(th);
        const float e0v = st * cosf(dp1) - 1.0f;
        const float e1v = st * sinf(dp1);
        const float e2v = cosf(th);
        const float d0 = cp*ca*e0v - sp*e1v + cp*sa*e2v;
        const float d1 = sp*ca*e0v + cp*e1v + sp*sa*e2v;
        const float d2 = -sa*e0v + ca*e2v;
        float Xn = X + runf*d0;
        float Yn = Y + runf*d1;
        float Zn = Z + runf*d2;
        Zn = (Zn < 0.f) ? -Zn : Zn;
        hit |= (Zn < 0.05f) ? 1 : 0;
        psum += Xn + Yn + Zn;
        const float g0 = gbuf[e*96 + 3*p + 0];
        const float g1 = gbuf[e*96 + 3*p + 1];
        const float g2 = gbuf[e*96 + 3*p + 2];
        const float r1 = -g0*sp + g1*cp;
        const float r2 = g0*cp*sa + g1*sp*sa + g2*ca;
        dpsum += (-r2)*dp0 + r1*dp1;
        xsT[(3*p + 0)*SX + e] = Xn;
        xsT[(3*p + 1)*SX + e] = Yn;
        xsT[(3*p + 2)*SX + e] = Zn;
    }
    #pragma unroll
    for (int m = 1; m <= 8; m <<= 1) {
        dpsum += __shfl_xor(dpsum, m);
        psum  += __shfl_xor(psum, m);
        hit   |= __shfl_xor(hit, m);
    }
    if (tt == 0) {
        const float pv = sP[e];
        const float rv = sRun[e];
        const float dp = -(0.2f * pv) * 0.01f + dpsum;
        sP[e] = pv + dp * rv;
        const bool rb = rv > 0.5f;
        if (rb && hit) sRel[e] = psum / 96.0f;
        sRun[e] = (rb && !hit) ? 1.0f : 0.0f;
    }
}

__global__ __launch_bounds__(256)
void sphere_ibsde_kernel_fb(
    const float* __restrict__ x0,  const float* __restrict__ dBt,
    const float* __restrict__ Dv,
    const float* __restrict__ pW1, const float* __restrict__ pb1,
    const float* __restrict__ pW2, const float* __restrict__ pb2,
    const float* __restrict__ pW3, const float* __restrict__ pb3,
    const float* __restrict__ gW1, const float* __restrict__ gb1,
    const float* __restrict__ gW2, const float* __restrict__ gb2,
    const float* __restrict__ gW3, const float* __restrict__ gb3,
    float* __restrict__ out)
{
    __shared__ float xsT[96 * SX];
    __shared__ float h1T[256 * SH];
    __shared__ float h2T[256 * SH];
    __shared__ float wbuf[16 * 256];
    __shared__ float sP[FNE], sRun[FNE], sRel[FNE];

    const int tid = threadIdx.x;
    const int b0 = blockIdx.x * FNE;

    #pragma unroll
    for (int i = 0; i < 6; ++i) {
        const int f = tid + i*256;
        const int e = f / 96, k = f - e*96;
        xsT[k*SX + e] = x0[(size_t)b0*96 + f];
    }

    layer256_fb(96,  pW1, pb1, xsT, SX, h1T, wbuf, tid);
    layer256_fb(256, pW2, pb2, h1T, SH, h2T, wbuf, tid);
    __syncthreads();
    {
        const int e = tid >> 4, tt = tid & 15;
        float s = 0.f;
        #pragma unroll
        for (int i = 0; i < 16; ++i) {
            const int k = tt + (i << 4);
            s += h2T[k*SH + e] * pW3[k];
        }
        #pragma unroll
        for (int m = 1; m <= 8; m <<= 1) s += __shfl_xor(s, m);
        if (tt == 0) { sP[e] = s + pb3[0]; sRun[e] = 1.0f; sRel[e] = 0.0f; }
    }

    const int ttc = tid & 15;
    const float s2d0 = sqrtf(2.0f * Dv[ttc]);
    const float s2d1 = sqrtf(2.0f * Dv[ttc + 16]);
    const float sqdt = sqrtf(0.01f);

    for (int t = 0; t < NSTEPS; ++t) {
        layer256_fb(96,  gW1 + (size_t)t*96*256,  gb1 + (size_t)t*256, xsT, SX, h1T, wbuf, tid);
        layer256_fb(256, gW2 + (size_t)t*256*256, gb2 + (size_t)t*256, h1T, SH, h2T, wbuf, tid);
        layer3_fb(gW3 + (size_t)t*256*96, gb3 + (size_t)t*96, h2T, wbuf, wbuf, tid);
        particles_step_fb(t, b0, dBt, s2d0, s2d1, sqdt, xsT, wbuf, sP, sRun, sRel, tid);
    }

    __syncthreads();
    {
        const int e = tid >> 4, tt = tid & 15;
        const int b = b0 + e;
        float s = 0.f;
        #pragma unroll
        for (int i = 0; i < 6; ++i) s += xsT[(tt*6 + i)*SX + e];
        #pragma unroll
        for (int m = 1; m <= 8; m <<= 1) s += __shfl_xor(s, m);
        if (tt == 0) {
            out[2*b] = sP[e];
            float pr = sRel[e];
            if (sRun[e] > 0.5f) pr = s / 96.0f;
            out[2*b + 1] = pr;
        }
    }
}

// =====================================================================
extern "C" void kernel_launch(void* const* d_in, const int* in_sizes, int n_in,
                              void* d_out, int out_size, void* d_ws, size_t ws_size,
                              hipStream_t stream)
{
    const float* x0  = (const float*)d_in[0];
    const float* dBt = (const float*)d_in[1];
    const float* Dv  = (const float*)d_in[2];
    const float* pW1 = (const float*)d_in[3];
    const float* pb1 = (const float*)d_in[4];
    const float* pW2 = (const float*)d_in[5];
    const float* pb2 = (const float*)d_in[6];
    const float* pW3 = (const float*)d_in[7];
    const float* pb3 = (const float*)d_in[8];
    const float* gW1 = (const float*)d_in[9];
    const float* gb1 = (const float*)d_in[10];
    const float* gW2 = (const float*)d_in[11];
    const float* gb2 = (const float*)d_in[12];
    const float* gW3 = (const float*)d_in[13];
    const float* gb3 = (const float*)d_in[14];
    float* out = (float*)d_out;

    const size_t A1 = (size_t)NSTEPS*256*96;
    const size_t A2 = (size_t)NSTEPS*256*256;
    const size_t A3 = (size_t)NSTEPS*96*256;
    const size_t P1 = 256*96;
    const size_t P2 = 256*256;
    const size_t total_elems = 2*(A1 + A2 + A3 + P1 + P2);

    if (ws_size >= total_elems * sizeof(short)) {
        short* p = (short*)d_ws;
        short* gW1h = p;            p += A1;
        short* gW1l = p;            p += A1;
        short* gW2h = p;            p += A2;
        short* gW2l = p;            p += A2;
        short* gW3h = p;            p += A3;
        short* gW3l = p;            p += A3;
        short* pW1h = p;            p += P1;
        short* pW1l = p;            p += P1;
        short* pW2h = p;            p += P2;
        short* pW2l = p;            p += P2;

        // [T][K][N] -> [T][N][K] split hi/lo, 32x32 tiles
        prep_split_tile<<<dim3(256/32,  96/32, NSTEPS), dim3(256), 0, stream>>>(gW1, gW1h, gW1l,  96, 256);
        prep_split_tile<<<dim3(256/32, 256/32, NSTEPS), dim3(256), 0, stream>>>(gW2, gW2h, gW2l, 256, 256);
        prep_split_tile<<<dim3( 96/32, 256/32, NSTEPS), dim3(256), 0, stream>>>(gW3, gW3h, gW3l, 256,  96);
        prep_split_tile<<<dim3(256/32,  96/32, 1),      dim3(256), 0, stream>>>(pW1, pW1h, pW1l,  96, 256);
        prep_split_tile<<<dim3(256/32, 256/32, 1),      dim3(256), 0, stream>>>(pW2, pW2h, pW2l, 256, 256);

        sphere_mfma_kernel<<<dim3(BATCH / NE), dim3(512), 0, stream>>>(
            x0, dBt, Dv,
            pW1h, pW1l, pb1, pW2h, pW2l, pb2, pW3, pb3,
            gW1h, gW1l, gb1, gW2h, gW2l, gb2, gW3h, gW3l, gb3, out);
    } else {
        sphere_ibsde_kernel_fb<<<dim3(BATCH / FNE), dim3(256), 0, stream>>>(
            x0, dBt, Dv, pW1, pb1, pW2, pb2, pW3, pb3,
            gW1, gb1, gW2, gb2, gW3, gb3, out);
    }
}

// Round 4
// 1111.473 us; speedup vs baseline: 2.3494x; 2.3494x over previous
//
#include <hip/hip_runtime.h>
#include <cstddef>

typedef short bfx8 __attribute__((ext_vector_type(8)));
typedef float f32x4 __attribute__((ext_vector_type(4)));

#define BATCH   4096
#define DXP     32
#define NSTEPS  100
#define NE      16      // batch elements per block (full 16-row MFMA tiles)
#define NWAVE   8       // waves per block
#define NJT     2       // j-tiles per wave in 256-wide layers (8w x 2 x 16 = 256)
#define KS      264     // A-buffer row stride in bf16 elems
#define XS      100     // xsF/gbuf row stride in floats
#define PIO2F   1.57079632679489662f

__device__ __forceinline__ unsigned short f2bf(float v){
    unsigned u = __float_as_uint(v);
    u += 0x7FFFu + ((u >> 16) & 1u);          // RNE
    return (unsigned short)(u >> 16);
}
__device__ __forceinline__ float bf2f(unsigned short h){
    return __uint_as_float(((unsigned)h) << 16);
}

// =====================================================================
// Prep: W [T][K][N] fp32 -> fragment-major split-bf16:
//   out[((t*NJ + jt)*KC + kc)*1024 + hl*512 + lane*8 + i]
// where n = jt*16 + m, k = kc*32 + q*8 + i, lane = q*16 + m.
// A wave's (jt,kc,hl) fragment is 1 KB contiguous -> coalesced loads.
// =====================================================================
__global__ __launch_bounds__(256)
void prep_frag_n256(const float* __restrict__ in, short* __restrict__ out, int K)
{
    const int bk = blockIdx.x;          // t*K + k
    const int t = bk / K, k = bk - t*K;
    const int n = threadIdx.x;          // 0..255, coalesced read
    const int KC = K >> 5;
    const float v = in[(size_t)bk*256 + n];
    const unsigned short h = f2bf(v);
    const unsigned short l = f2bf(v - bf2f(h));
    const int jt = n >> 4, m = n & 15;
    const int kc = k >> 5, q = (k >> 3) & 3, i = k & 7;
    const size_t base = ((size_t)(t*16 + jt)*KC + kc)*1024 + (q*16 + m)*8 + i;
    out[base]       = (short)h;
    out[base + 512] = (short)l;
}

// N=96 (layer-3 weights): two k-rows per block, NJ=6, K=256.
__global__ __launch_bounds__(256)
void prep_frag_n96(const float* __restrict__ in, short* __restrict__ out, int K)
{
    const int bk = blockIdx.x;          // t*(K/2) + kpair
    const int K2 = K >> 1;
    const int t = bk / K2, kp = bk - t*K2;
    const int tid = threadIdx.x;
    if (tid >= 192) return;
    const int koff = (tid >= 96) ? 1 : 0;
    const int n = tid - 96*koff;        // 0..95
    const int k = kp*2 + koff;
    const float v = in[((size_t)(t*K + k))*96 + n];
    const unsigned short h = f2bf(v);
    const unsigned short l = f2bf(v - bf2f(h));
    const int jt = n >> 4, m = n & 15;
    const int kc = k >> 5, q = (k >> 3) & 3, i = k & 7;
    const size_t base = ((size_t)(t*6 + jt)*8 + kc)*1024 + (q*16 + m)*8 + i;
    out[base]       = (short)h;
    out[base + 512] = (short)l;
}

// =====================================================================
// Hidden layer: 16m x 256j, K = KC*32, tanh, split-bf16 out.
// Full-layer B preload (coalesced fragment loads, issued BEFORE the
// barrier so latency overlaps the previous stage's epilogue).
// =====================================================================
template<int KC>
__device__ __forceinline__ void layer_hidden(
    const short* __restrict__ Wf,       // step base, fragment layout, 16 jtiles
    const float* __restrict__ bias,
    const short* __restrict__ inH, const short* __restrict__ inL,
    short* __restrict__ outH, short* __restrict__ outL,
    int lane, int wid)
{
    const int m = lane & 15, q = lane >> 4;
    const short* wb = Wf + (size_t)(wid*NJT)*KC*1024 + lane*8;

    bfx8 B[KC*NJT*2];
    #pragma unroll
    for (int kc = 0; kc < KC; ++kc)
        #pragma unroll
        for (int jj = 0; jj < NJT; ++jj) {
            B[(kc*NJT + jj)*2 + 0] = *(const bfx8*)(wb + ((size_t)(jj*KC + kc)*2 + 0)*512);
            B[(kc*NJT + jj)*2 + 1] = *(const bfx8*)(wb + ((size_t)(jj*KC + kc)*2 + 1)*512);
        }

    f32x4 acc[NJT];
    #pragma unroll
    for (int jj = 0; jj < NJT; ++jj) acc[jj] = (f32x4){0.f,0.f,0.f,0.f};

    __syncthreads();   // in-buffer written; out-buffer's prior readers done

    const short* aph = inH + m*KS + q*8;
    const short* apl = inL + m*KS + q*8;

    #pragma unroll
    for (int kc = 0; kc < KC; ++kc) {
        const bfx8 ah = *(const bfx8*)(aph + kc*32);
        const bfx8 al = *(const bfx8*)(apl + kc*32);
        #pragma unroll
        for (int jj = 0; jj < NJT; ++jj) {
            acc[jj] = __builtin_amdgcn_mfma_f32_16x16x32_bf16(ah, B[(kc*NJT+jj)*2+0], acc[jj], 0, 0, 0);
            acc[jj] = __builtin_amdgcn_mfma_f32_16x16x32_bf16(al, B[(kc*NJT+jj)*2+0], acc[jj], 0, 0, 0);
            acc[jj] = __builtin_amdgcn_mfma_f32_16x16x32_bf16(ah, B[(kc*NJT+jj)*2+1], acc[jj], 0, 0, 0);
        }
    }
    // epilogue: C row = batch elem (q*4+r), col = j (m)
    #pragma unroll
    for (int jj = 0; jj < NJT; ++jj) {
        const int cj = (wid*NJT + jj)*16 + m;
        const float bv = bias[cj];
        #pragma unroll
        for (int r = 0; r < 4; ++r) {
            const float v = tanhf(acc[jj][r] + bv);
            const unsigned short h = f2bf(v);
            const int row = q*4 + r;
            outH[row*KS + cj] = (short)h;
            outL[row*KS + cj] = (short)f2bf(v - bf2f(h));
        }
    }
}

// =====================================================================
// pMLP layer2 fused with pW3 dot (K=256, fragment layout).
// =====================================================================
__device__ __forceinline__ void p_l2_dot(
    const short* __restrict__ Wf,
    const float* __restrict__ pb2, const float* __restrict__ pW3,
    const short* __restrict__ inH, const short* __restrict__ inL,
    float* __restrict__ sPpart, int lane, int wid)
{
    const int m = lane & 15, q = lane >> 4;
    const short* wb = Wf + (size_t)(wid*NJT)*8*1024 + lane*8;

    bfx8 B[8*NJT*2];
    #pragma unroll
    for (int kc = 0; kc < 8; ++kc)
        #pragma unroll
        for (int jj = 0; jj < NJT; ++jj) {
            B[(kc*NJT + jj)*2 + 0] = *(const bfx8*)(wb + ((size_t)(jj*8 + kc)*2 + 0)*512);
            B[(kc*NJT + jj)*2 + 1] = *(const bfx8*)(wb + ((size_t)(jj*8 + kc)*2 + 1)*512);
        }

    f32x4 acc[NJT];
    #pragma unroll
    for (int jj = 0; jj < NJT; ++jj) acc[jj] = (f32x4){0.f,0.f,0.f,0.f};

    __syncthreads();

    const short* aph = inH + m*KS + q*8;
    const short* apl = inL + m*KS + q*8;

    #pragma unroll
    for (int kc = 0; kc < 8; ++kc) {
        const bfx8 ah = *(const bfx8*)(aph + kc*32);
        const bfx8 al = *(const bfx8*)(apl + kc*32);
        #pragma unroll
        for (int jj = 0; jj < NJT; ++jj) {
            acc[jj] = __builtin_amdgcn_mfma_f32_16x16x32_bf16(ah, B[(kc*NJT+jj)*2+0], acc[jj], 0, 0, 0);
            acc[jj] = __builtin_amdgcn_mfma_f32_16x16x32_bf16(al, B[(kc*NJT+jj)*2+0], acc[jj], 0, 0, 0);
            acc[jj] = __builtin_amdgcn_mfma_f32_16x16x32_bf16(ah, B[(kc*NJT+jj)*2+1], acc[jj], 0, 0, 0);
        }
    }
    float ps[4] = {0.f, 0.f, 0.f, 0.f};
    #pragma unroll
    for (int jj = 0; jj < NJT; ++jj) {
        const int cj = (wid*NJT + jj)*16 + m;
        const float bv = pb2[cj];
        const float w3 = pW3[cj];
        #pragma unroll
        for (int r = 0; r < 4; ++r)
            ps[r] += tanhf(acc[jj][r] + bv) * w3;
    }
    #pragma unroll
    for (int mask = 1; mask <= 8; mask <<= 1) {
        #pragma unroll
        for (int r = 0; r < 4; ++r) ps[r] += __shfl_xor(ps[r], mask);
    }
    if (m == 0) {
        #pragma unroll
        for (int r = 0; r < 4; ++r) sPpart[wid*16 + q*4 + r] = ps[r];
    }
}

// =====================================================================
// Layer 3: 16m x 96o, K=256, no act, fp32 out gbuf [e][o] stride XS.
// 6 jtiles; waves 0-5 take one each, waves 6-7 idle.
// =====================================================================
__device__ __forceinline__ void layer_out(
    const short* __restrict__ Wf, const float* __restrict__ bias,
    const short* __restrict__ inH, const short* __restrict__ inL,
    float* __restrict__ gbuf, int lane, int wid)
{
    const int m = lane & 15, q = lane >> 4;
    bfx8 B[16];
    if (wid < 6) {
        const short* wb = Wf + (size_t)wid*8*1024 + lane*8;
        #pragma unroll
        for (int kc = 0; kc < 8; ++kc) {
            B[kc*2 + 0] = *(const bfx8*)(wb + ((size_t)kc*2 + 0)*512);
            B[kc*2 + 1] = *(const bfx8*)(wb + ((size_t)kc*2 + 1)*512);
        }
    }
    __syncthreads();
    if (wid < 6) {
        const short* aph = inH + m*KS + q*8;
        const short* apl = inL + m*KS + q*8;
        f32x4 acc = (f32x4){0.f,0.f,0.f,0.f};
        #pragma unroll
        for (int kc = 0; kc < 8; ++kc) {
            const bfx8 ah = *(const bfx8*)(aph + kc*32);
            const bfx8 al = *(const bfx8*)(apl + kc*32);
            acc = __builtin_amdgcn_mfma_f32_16x16x32_bf16(ah, B[kc*2+0], acc, 0, 0, 0);
            acc = __builtin_amdgcn_mfma_f32_16x16x32_bf16(al, B[kc*2+0], acc, 0, 0, 0);
            acc = __builtin_amdgcn_mfma_f32_16x16x32_bf16(ah, B[kc*2+1], acc, 0, 0, 0);
        }
        const int cj = wid*16 + m;
        const float bv = bias[cj];
        #pragma unroll
        for (int r = 0; r < 4; ++r)
            gbuf[(q*4 + r)*XS + cj] = acc[r] + bv;
    }
}

// =====================================================================
// Particle / SDE update: 1 thread = 1 particle, all 512 threads.
// fp32 exact, contract off. Bit-identical math to rounds 1-3.
// =====================================================================
__device__ __forceinline__ void particles_step2(
    int t, int b0, const float* __restrict__ dBt,
    float s2d, float sqdt,
    float* __restrict__ xsF, const float* __restrict__ gbuf,
    short* __restrict__ xH, short* __restrict__ xL,
    float* __restrict__ sP, float* __restrict__ sRun, float* __restrict__ sRel,
    int tid)
{
#pragma clang fp contract(off)
    const int e = tid >> 5;          // 0..15
    const int p = tid & 31;          // particle
    const int b = b0 + e;
    const float runf = sRun[e];

    const float2 db = *(const float2*)(dBt + (((size_t)t*BATCH + b)*DXP + p)*2);
    const float db0 = db.x * sqdt;
    const float db1 = db.y * sqdt;
    const float dp0 = s2d * db0;
    const float dp1 = s2d * db1;
    const float X = xsF[e*XS + 3*p + 0];
    const float Y = xsF[e*XS + 3*p + 1];
    const float Z = xsF[e*XS + 3*p + 2];
    const float zc = fminf(fmaxf(Z, -0.999999f), 0.999999f);
    const float theta = acosf(zc);
    const float phi = atan2f(Y, X);
    const float aa = theta - PIO2F;
    const float ca = cosf(aa), sa = sinf(aa);
    const float cp = cosf(phi), sp = sinf(phi);
    const float th = dp0 + PIO2F;
    const float st = sinf(th);
    const float e0v = st * cosf(dp1) - 1.0f;
    const float e1v = st * sinf(dp1);
    const float e2v = cosf(th);
    const float d0 = cp*ca*e0v - sp*e1v + cp*sa*e2v;
    const float d1 = sp*ca*e0v + cp*e1v + sp*sa*e2v;
    const float d2 = -sa*e0v + ca*e2v;
    float Xn = X + runf*d0;
    float Yn = Y + runf*d1;
    float Zn = Z + runf*d2;
    Zn = (Zn < 0.f) ? -Zn : Zn;
    int   hit   = (Zn < 0.05f) ? 1 : 0;
    float psum  = Xn + Yn + Zn;
    const float g0 = gbuf[e*XS + 3*p + 0];
    const float g1 = gbuf[e*XS + 3*p + 1];
    const float g2 = gbuf[e*XS + 3*p + 2];
    const float r1 = -g0*sp + g1*cp;
    const float r2 = g0*cp*sa + g1*sp*sa + g2*ca;
    float dpsum = (-r2)*dp0 + r1*dp1;

    xsF[e*XS + 3*p + 0] = Xn;
    xsF[e*XS + 3*p + 1] = Yn;
    xsF[e*XS + 3*p + 2] = Zn;
    const float nv[3] = {Xn, Yn, Zn};
    #pragma unroll
    for (int c = 0; c < 3; ++c) {
        const unsigned short h = f2bf(nv[c]);
        xH[e*KS + 3*p + c] = (short)h;
        xL[e*KS + 3*p + c] = (short)f2bf(nv[c] - bf2f(h));
    }
    #pragma unroll
    for (int mask = 1; mask <= 16; mask <<= 1) {
        dpsum += __shfl_xor(dpsum, mask);
        psum  += __shfl_xor(psum, mask);
        hit   |= __shfl_xor(hit, mask);
    }
    if (p == 0) {
        const float pv = sP[e];
        const float rv = runf;
        const float dp = -(0.2f * pv) * 0.01f + dpsum;
        sP[e] = pv + dp * rv;
        const bool rb = rv > 0.5f;
        if (rb && hit) sRel[e] = psum / 96.0f;
        sRun[e] = (rb && !hit) ? 1.0f : 0.0f;
    }
}

__global__ __launch_bounds__(512, 2)
void sphere_mfma_kernel(
    const float* __restrict__ x0,  const float* __restrict__ dBt,
    const float* __restrict__ Dv,
    const short* __restrict__ pW1f, const float* __restrict__ pb1,
    const short* __restrict__ pW2f, const float* __restrict__ pb2,
    const float* __restrict__ pW3,  const float* __restrict__ pb3,
    const short* __restrict__ gW1f, const float* __restrict__ gb1,
    const short* __restrict__ gW2f, const float* __restrict__ gb2,
    const short* __restrict__ gW3f, const float* __restrict__ gb3,
    float* __restrict__ out)
{
    __shared__ short aH0[16*KS], aL0[16*KS], aH1[16*KS], aL1[16*KS];
    __shared__ float xsF[NE*XS], gbuf[NE*XS];
    __shared__ float sPpart[NWAVE*16];
    __shared__ float sP[NE], sRun[NE], sRel[NE];

    const int tid  = threadIdx.x;
    const int lane = tid & 63, wid = tid >> 6;
    const int b0   = blockIdx.x * NE;

    // x0 -> xsF (fp32) + split-bf16 A buffer, rows 0..15
    for (int i = tid; i < NE*96; i += 512) {
        const int e = i / 96, k = i - e*96;
        const float v = x0[(size_t)b0*96 + i];
        xsF[e*XS + k] = v;
        const unsigned short h = f2bf(v);
        aH0[e*KS + k] = (short)h;
        aL0[e*KS + k] = (short)f2bf(v - bf2f(h));
    }

    // ---- p0 = pMLP(x0), layer2 fused with pW3 dot ----
    layer_hidden<3>(pW1f, pb1, aH0, aL0, aH1, aL1, lane, wid);
    p_l2_dot(pW2f, pb2, pW3, aH1, aL1, sPpart, lane, wid);
    __syncthreads();
    if (tid < NE) {
        float s = pb3[0];
        #pragma unroll
        for (int w = 0; w < NWAVE; ++w) s += sPpart[w*16 + tid];
        sP[tid] = s; sRun[tid] = 1.0f; sRel[tid] = 0.0f;
    }

    const float s2d  = sqrtf(2.0f * Dv[tid & 31]);
    const float sqdt = sqrtf(0.01f);

    // ---- 100 scan steps, 4 barriers each ----
    for (int t = 0; t < NSTEPS; ++t) {
        layer_hidden<3>(gW1f + (size_t)t*49152,  gb1 + (size_t)t*256,
                        aH0, aL0, aH1, aL1, lane, wid);
        layer_hidden<8>(gW2f + (size_t)t*131072, gb2 + (size_t)t*256,
                        aH1, aL1, aH0, aL0, lane, wid);
        layer_out(gW3f + (size_t)t*49152, gb3 + (size_t)t*96,
                  aH0, aL0, gbuf, lane, wid);
        __syncthreads();
        particles_step2(t, b0, dBt, s2d, sqdt, xsF, gbuf, aH0, aL0,
                        sP, sRun, sRel, tid);
    }

    // ---- finalize ----
    __syncthreads();
    {
        const int e = tid >> 5, tt = tid & 31;
        const int b = b0 + e;
        float s = xsF[e*XS + 3*tt] + xsF[e*XS + 3*tt + 1] + xsF[e*XS + 3*tt + 2];
        #pragma unroll
        for (int mask = 1; mask <= 16; mask <<= 1) s += __shfl_xor(s, mask);
        if (tt == 0) {
            out[2*b] = sP[e];
            float pr = sRel[e];
            if (sRun[e] > 0.5f) pr = s / 96.0f;
            out[2*b + 1] = pr;
        }
    }
}

// =====================================================================
// ===================== FALLBACK (fp32, round-1) ======================
// =====================================================================
#define FNE 16
#define SH 20
#define SX 16

__device__ __forceinline__ void layer256_fb(
    int K, const float* __restrict__ W, const float* __restrict__ bias,
    const float* __restrict__ in_lds, int in_stride,
    float* __restrict__ out_lds, float* __restrict__ wbuf, int tid)
{
    const int jg = tid & 63;
    const int eg = tid >> 6;
    const int j0 = jg << 2;
    const int e0 = eg << 2;
    float acc[4][4];
    #pragma unroll
    for (int ee = 0; ee < 4; ++ee)
        #pragma unroll
        for (int jj = 0; jj < 4; ++jj) acc[ee][jj] = 0.f;
    const int nc = K >> 4;
    const float4* __restrict__ Wv = (const float4*)W;
    float4* wv = (float4*)wbuf;
    float4 pre[4];
    #pragma unroll
    for (int i = 0; i < 4; ++i) pre[i] = Wv[tid + i*256];
    for (int c = 0; c < nc; ++c) {
        __syncthreads();
        #pragma unroll
        for (int i = 0; i < 4; ++i) wv[tid + i*256] = pre[i];
        if (c + 1 < nc) {
            #pragma unroll
            for (int i = 0; i < 4; ++i) pre[i] = Wv[(c+1)*1024 + tid + i*256];
        }
        __syncthreads();
        const float* inb = in_lds + (c << 4) * in_stride + e0;
        #pragma unroll
        for (int kk = 0; kk < 16; ++kk) {
            const float4 a = *(const float4*)(inb + kk * in_stride);
            const float4 w = *(const float4*)(wbuf + kk*256 + j0);
            const float av[4] = {a.x, a.y, a.z, a.w};
            const float wl[4] = {w.x, w.y, w.z, w.w};
            #pragma unroll
            for (int ee = 0; ee < 4; ++ee)
                #pragma unroll
                for (int jj = 0; jj < 4; ++jj)
                    acc[ee][jj] += av[ee] * wl[jj];
        }
    }
    const float4 bb = *(const float4*)(bias + j0);
    const float bv[4] = {bb.x, bb.y, bb.z, bb.w};
    #pragma unroll
    for (int jj = 0; jj < 4; ++jj) {
        float4 v;
        v.x = tanhf(acc[0][jj] + bv[jj]);
        v.y = tanhf(acc[1][jj] + bv[jj]);
        v.z = tanhf(acc[2][jj] + bv[jj]);
        v.w = tanhf(acc[3][jj] + bv[jj]);
        *(float4*)(out_lds + (j0 + jj) * SH + e0) = v;
    }
}

__device__ __forceinline__ void layer3_fb(
    const float* __restrict__ W, const float* __restrict__ bias,
    const float* __restrict__ h2, float* __restrict__ wbuf,
    float* __restrict__ gbuf, int tid)
{
    const int og = tid & 31;
    const int eg = tid >> 5;
    const int o0 = og * 3;
    const int e0 = eg << 1;
    float acc[2][3];
    #pragma unroll
    for (int ee = 0; ee < 2; ++ee)
        #pragma unroll
        for (int oo = 0; oo < 3; ++oo) acc[ee][oo] = 0.f;
    const float2* __restrict__ Wv = (const float2*)W;
    float2* wv2 = (float2*)wbuf;
    float2 pre[3];
    #pragma unroll
    for (int i = 0; i < 3; ++i) pre[i] = Wv[tid + i*256];
    for (int c = 0; c < 16; ++c) {
        __syncthreads();
        #pragma unroll
        for (int i = 0; i < 3; ++i) wv2[tid + i*256] = pre[i];
        if (c + 1 < 16) {
            #pragma unroll
            for (int i = 0; i < 3; ++i) pre[i] = Wv[(c+1)*768 + tid + i*256];
        }
        __syncthreads();
        #pragma unroll
        for (int kk = 0; kk < 16; ++kk) {
            const float2 a = *(const float2*)(h2 + (c*16 + kk)*SH + e0);
            const float* wr = wbuf + kk*96 + o0;
            const float w0 = wr[0], w1 = wr[1], w2 = wr[2];
            acc[0][0] += a.x*w0; acc[0][1] += a.x*w1; acc[0][2] += a.x*w2;
            acc[1][0] += a.y*w0; acc[1][1] += a.y*w1; acc[1][2] += a.y*w2;
        }
    }
    __syncthreads();
    #pragma unroll
    for (int ee = 0; ee < 2; ++ee)
        #pragma unroll
        for (int oo = 0; oo < 3; ++oo)
            gbuf[(e0 + ee)*96 + o0 + oo] = acc[ee][oo] + bias[o0 + oo];
    __syncthreads();
}

__device__ __forceinline__ void particles_step_fb(
    int t, int b0, const float* __restrict__ dBt,
    float s2d0, float s2d1, float sqdt,
    float* __restrict__ xsT, const float* __restrict__ gbuf,
    float* __restrict__ sP, float* __restrict__ sRun, float* __restrict__ sRel,
    int tid)
{
#pragma clang fp contract(off)
    const int e  = tid >> 4;
    const int tt = tid & 15;
    const int b  = b0 + e;
    const float runf = sRun[e];
    float dpsum = 0.f, psum = 0.f;
    int hit = 0;
    #pragma unroll
    for (int pp = 0; pp < 2; ++pp) {
        const int p = tt + (pp << 4);
        const float s2d = pp ? s2d1 : s2d0;
        const float2 db = *(const float2*)(dBt + (((size_t)t*BATCH + b)*DXP + p)*2);
        const float db0 = db.x * sqdt;
        const float db1 = db.y * sqdt;
        const float dp0 = s2d * db0;
        const float dp1 = s2d * db1;
        const float X = xsT[(3*p + 0)*SX + e];
        const float Y = xsT[(3*p + 1)*SX + e];
        const float Z = xsT[(3*p + 2)*SX + e];
        const float zc = fminf(fmaxf(Z, -0.999999f), 0.999999f);
        const float theta = acosf(zc);
        const float phi = atan2f(Y, X);
        const float aa = theta - PIO2F;
        const float ca = cosf(aa), sa = sinf(aa);
        const float cp = cosf(phi), sp = sinf(phi);
        const float th = dp0 + PIO2F;
        const float st = sinf(th);
        const float e0v = st * cosf(dp1) - 1.0f;
        const float e1v = st * sinf(dp1);
        const float e2v = cosf(th);
        const float d0 = cp*ca*e0v - sp*e1v + cp*sa*e2v;
        const float d1 = sp*ca*e0v + cp*e1v + sp*sa*e2v;
        const float d2 = -sa*e0v + ca*e2v;
        float Xn = X + runf*d0;
        float Yn = Y + runf*d1;
        float Zn = Z + runf*d2;
        Zn = (Zn < 0.f) ? -Zn : Zn;
        hit |= (Zn < 0.05f) ? 1 : 0;
        psum += Xn + Yn + Zn;
        const float g0 = gbuf[e*96 + 3*p + 0];
        const float g1 = gbuf[e*96 + 3*p + 1];
        const float g2 = gbuf[e*96 + 3*p + 2];
        const float r1 = -g0*sp + g1*cp;
        const float r2 = g0*cp*sa + g1*sp*sa + g2*ca;
        dpsum += (-r2)*dp0 + r1*dp1;
        xsT[(3*p + 0)*SX + e] = Xn;
        xsT[(3*p + 1)*SX + e] = Yn;
        xsT[(3*p + 2)*SX + e] = Zn;
    }
    #pragma unroll
    for (int m = 1; m <= 8; m <<= 1) {
        dpsum += __shfl_xor(dpsum, m);
        psum  += __shfl_xor(psum, m);
        hit   |= __shfl_xor(hit, m);
    }
    if (tt == 0) {
        const float pv = sP[e];
        const float rv = sRun[e];
        const float dp = -(0.2f * pv) * 0.01f + dpsum;
        sP[e] = pv + dp * rv;
        const bool rb = rv > 0.5f;
        if (rb && hit) sRel[e] = psum / 96.0f;
        sRun[e] = (rb && !hit) ? 1.0f : 0.0f;
    }
}

__global__ __launch_bounds__(256)
void sphere_ibsde_kernel_fb(
    const float* __restrict__ x0,  const float* __restrict__ dBt,
    const float* __restrict__ Dv,
    const float* __restrict__ pW1, const float* __restrict__ pb1,
    const float* __restrict__ pW2, const float* __restrict__ pb2,
    const float* __restrict__ pW3, const float* __restrict__ pb3,
    const float* __restrict__ gW1, const float* __restrict__ gb1,
    const float* __restrict__ gW2, const float* __restrict__ gb2,
    const float* __restrict__ gW3, const float* __restrict__ gb3,
    float* __restrict__ out)
{
    __shared__ float xsT[96 * SX];
    __shared__ float h1T[256 * SH];
    __shared__ float h2T[256 * SH];
    __shared__ float wbuf[16 * 256];
    __shared__ float sP[FNE], sRun[FNE], sRel[FNE];

    const int tid = threadIdx.x;
    const int b0 = blockIdx.x * FNE;

    #pragma unroll
    for (int i = 0; i < 6; ++i) {
        const int f = tid + i*256;
        const int e = f / 96, k = f - e*96;
        xsT[k*SX + e] = x0[(size_t)b0*96 + f];
    }

    layer256_fb(96,  pW1, pb1, xsT, SX, h1T, wbuf, tid);
    layer256_fb(256, pW2, pb2, h1T, SH, h2T, wbuf, tid);
    __syncthreads();
    {
        const int e = tid >> 4, tt = tid & 15;
        float s = 0.f;
        #pragma unroll
        for (int i = 0; i < 16; ++i) {
            const int k = tt + (i << 4);
            s += h2T[k*SH + e] * pW3[k];
        }
        #pragma unroll
        for (int m = 1; m <= 8; m <<= 1) s += __shfl_xor(s, m);
        if (tt == 0) { sP[e] = s + pb3[0]; sRun[e] = 1.0f; sRel[e] = 0.0f; }
    }

    const int ttc = tid & 15;
    const float s2d0 = sqrtf(2.0f * Dv[ttc]);
    const float s2d1 = sqrtf(2.0f * Dv[ttc + 16]);
    const float sqdt = sqrtf(0.01f);

    for (int t = 0; t < NSTEPS; ++t) {
        layer256_fb(96,  gW1 + (size_t)t*96*256,  gb1 + (size_t)t*256, xsT, SX, h1T, wbuf, tid);
        layer256_fb(256, gW2 + (size_t)t*256*256, gb2 + (size_t)t*256, h1T, SH, h2T, wbuf, tid);
        layer3_fb(gW3 + (size_t)t*256*96, gb3 + (size_t)t*96, h2T, wbuf, wbuf, tid);
        particles_step_fb(t, b0, dBt, s2d0, s2d1, sqdt, xsT, wbuf, sP, sRun, sRel, tid);
    }

    __syncthreads();
    {
        const int e = tid >> 4, tt = tid & 15;
        const int b = b0 + e;
        float s = 0.f;
        #pragma unroll
        for (int i = 0; i < 6; ++i) s += xsT[(tt*6 + i)*SX + e];
        #pragma unroll
        for (int m = 1; m <= 8; m <<= 1) s += __shfl_xor(s, m);
        if (tt == 0) {
            out[2*b] = sP[e];
            float pr = sRel[e];
            if (sRun[e] > 0.5f) pr = s / 96.0f;
            out[2*b + 1] = pr;
        }
    }
}

// =====================================================================
extern "C" void kernel_launch(void* const* d_in, const int* in_sizes, int n_in,
                              void* d_out, int out_size, void* d_ws, size_t ws_size,
                              hipStream_t stream)
{
    const float* x0  = (const float*)d_in[0];
    const float* dBt = (const float*)d_in[1];
    const float* Dv  = (const float*)d_in[2];
    const float* pW1 = (const float*)d_in[3];
    const float* pb1 = (const float*)d_in[4];
    const float* pW2 = (const float*)d_in[5];
    const float* pb2 = (const float*)d_in[6];
    const float* pW3 = (const float*)d_in[7];
    const float* pb3 = (const float*)d_in[8];
    const float* gW1 = (const float*)d_in[9];
    const float* gb1 = (const float*)d_in[10];
    const float* gW2 = (const float*)d_in[11];
    const float* gb2 = (const float*)d_in[12];
    const float* gW3 = (const float*)d_in[13];
    const float* gb3 = (const float*)d_in[14];
    float* out = (float*)d_out;

    // fragment-layout sizes in shorts (hi+lo interleaved per fragment pair)
    const size_t A1 = (size_t)NSTEPS * 16 * 3 * 1024;   // 4,915,200
    const size_t A2 = (size_t)NSTEPS * 16 * 8 * 1024;   // 13,107,200
    const size_t A3 = (size_t)NSTEPS *  6 * 8 * 1024;   // 4,915,200
    const size_t P1 = (size_t)16 * 3 * 1024;            // 49,152
    const size_t P2 = (size_t)16 * 8 * 1024;            // 131,072
    const size_t total_elems = A1 + A2 + A3 + P1 + P2;

    if (ws_size >= total_elems * sizeof(short)) {
        short* p = (short*)d_ws;
        short* gW1f = p;            p += A1;
        short* gW2f = p;            p += A2;
        short* gW3f = p;            p += A3;
        short* pW1f = p;            p += P1;
        short* pW2f = p;            p += P2;

        prep_frag_n256<<<dim3(NSTEPS*96),  dim3(256), 0, stream>>>(gW1, gW1f, 96);
        prep_frag_n256<<<dim3(NSTEPS*256), dim3(256), 0, stream>>>(gW2, gW2f, 256);
        prep_frag_n96 <<<dim3(NSTEPS*128), dim3(256), 0, stream>>>(gW3, gW3f, 256);
        prep_frag_n256<<<dim3(96),         dim3(256), 0, stream>>>(pW1, pW1f, 96);
        prep_frag_n256<<<dim3(256),        dim3(256), 0, stream>>>(pW2, pW2f, 256);

        sphere_mfma_kernel<<<dim3(BATCH / NE), dim3(512), 0, stream>>>(
            x0, dBt, Dv,
            pW1f, pb1, pW2f, pb2, pW3, pb3,
            gW1f, gb1, gW2f, gb2, gW3f, gb3, out);
    } else {
        sphere_ibsde_kernel_fb<<<dim3(BATCH / FNE), dim3(256), 0, stream>>>(
            x0, dBt, Dv, pW1, pb1, pW2, pb2, pW3, pb3,
            gW1, gb1, gW2, gb2, gW3, gb3, out);
    }
}

// Round 5
// 975.437 us; speedup vs baseline: 2.6770x; 1.1395x over previous
//
#include <hip/hip_runtime.h>
#include <cstddef>

typedef short bfx8 __attribute__((ext_vector_type(8)));
typedef float f32x4 __attribute__((ext_vector_type(4)));

#define BATCH   4096
#define DXP     32
#define NSTEPS  100
#define NE      16      // batch elements per block (full 16-row MFMA tiles)
#define NWAVE   16      // waves per block (block = 1024)
#define KS      264     // A-buffer row stride in bf16 elems
#define XS      100     // xsF/gbuf row stride in floats
#define PIO2F   1.57079632679489662f

__device__ __forceinline__ unsigned short f2bf(float v){
    unsigned u = __float_as_uint(v);
    u += 0x7FFFu + ((u >> 16) & 1u);          // RNE
    return (unsigned short)(u >> 16);
}
__device__ __forceinline__ float bf2f(unsigned short h){
    return __uint_as_float(((unsigned)h) << 16);
}
// fast tanh: only feeds the smooth p-path (positions never depend on MLP),
// ~1e-6 abs error vs 4e-2 budget. Saturates correctly at +/-1.
__device__ __forceinline__ float fast_tanh(float x){
    const float e2 = __expf(2.0f * x);
    return 1.0f - __fdividef(2.0f, e2 + 1.0f);
}

// =====================================================================
// Prep: W [T][K][N] fp32 -> fragment-major split-bf16 (same layout as R4):
//   out[((t*NJ + jt)*KC + kc)*1024 + hl*512 + (q*16+m)*8 + i]
//   n = jt*16 + m, k = kc*32 + q*8 + i.
// One block per (t,kc,q): each thread packs 8 consecutive k into one
// contiguous 16B store (coalesced read AND write).
// =====================================================================
__global__ __launch_bounds__(256)
void prep_frag_n256(const float* __restrict__ in, short* __restrict__ out, int K)
{
    const int KC = K >> 5;
    int b = blockIdx.x;                 // t*KC*4 + kc*4 + q
    const int q = b & 3; b >>= 2;
    const int kc = b % KC, t = b / KC;
    const int n = threadIdx.x;
    const int jt = n >> 4, m = n & 15;
    bfx8 hv, lv;
    #pragma unroll
    for (int i = 0; i < 8; ++i) {
        const int k = kc*32 + q*8 + i;
        const float v = in[((size_t)t*K + k)*256 + n];
        const unsigned short h = f2bf(v);
        hv[i] = (short)h;
        lv[i] = (short)f2bf(v - bf2f(h));
    }
    const size_t base = ((size_t)(t*16 + jt)*KC + kc)*1024 + (q*16 + m)*8;
    *(bfx8*)(out + base)       = hv;
    *(bfx8*)(out + base + 512) = lv;
}

// N=96 (layer-3 weights), K=256, NJ=6. One block per (t,kc,q).
__global__ __launch_bounds__(128)
void prep_frag_n96(const float* __restrict__ in, short* __restrict__ out)
{
    int b = blockIdx.x;                 // t*32 + kc*4 + q
    const int q = b & 3; b >>= 2;
    const int kc = b & 7, t = b >> 3;
    const int n = threadIdx.x;
    if (n >= 96) return;
    const int jt = n >> 4, m = n & 15;
    bfx8 hv, lv;
    #pragma unroll
    for (int i = 0; i < 8; ++i) {
        const int k = kc*32 + q*8 + i;
        const float v = in[((size_t)t*256 + k)*96 + n];
        const unsigned short h = f2bf(v);
        hv[i] = (short)h;
        lv[i] = (short)f2bf(v - bf2f(h));
    }
    const size_t base = ((size_t)(t*6 + jt)*8 + kc)*1024 + (q*16 + m)*8;
    *(bfx8*)(out + base)       = hv;
    *(bfx8*)(out + base + 512) = lv;
}

// =====================================================================
// Hidden layer: 16m x 256j, K = KC*32, fast-tanh, split-bf16 out.
// Wave w owns j-tile w (16 waves x 16 = 256). Full B preload before the
// barrier; two accumulators break the 3-MFMA dependency chain.
// =====================================================================
template<int KC>
__device__ __forceinline__ void layer_hidden(
    const short* __restrict__ Wf, const float* __restrict__ bias,
    const short* __restrict__ inH, const short* __restrict__ inL,
    short* __restrict__ outH, short* __restrict__ outL,
    int lane, int wid)
{
    const int m = lane & 15, q = lane >> 4;
    const short* wb = Wf + (size_t)wid*KC*1024 + lane*8;

    bfx8 bh[KC], bl[KC];
    #pragma unroll
    for (int kc = 0; kc < KC; ++kc) {
        bh[kc] = *(const bfx8*)(wb + (size_t)kc*1024);
        bl[kc] = *(const bfx8*)(wb + (size_t)kc*1024 + 512);
    }
    f32x4 acc0 = (f32x4){0.f,0.f,0.f,0.f};
    f32x4 acc1 = (f32x4){0.f,0.f,0.f,0.f};

    __syncthreads();   // in-buffer written; out-buffer's prior readers done

    const short* aph = inH + m*KS + q*8;
    const short* apl = inL + m*KS + q*8;

    #pragma unroll
    for (int kc = 0; kc < KC; ++kc) {
        const bfx8 ah = *(const bfx8*)(aph + kc*32);
        const bfx8 al = *(const bfx8*)(apl + kc*32);
        acc0 = __builtin_amdgcn_mfma_f32_16x16x32_bf16(ah, bh[kc], acc0, 0, 0, 0);
        acc1 = __builtin_amdgcn_mfma_f32_16x16x32_bf16(al, bh[kc], acc1, 0, 0, 0);
        acc1 = __builtin_amdgcn_mfma_f32_16x16x32_bf16(ah, bl[kc], acc1, 0, 0, 0);
    }
    const int cj = wid*16 + m;
    const float bv = bias[cj];
    #pragma unroll
    for (int r = 0; r < 4; ++r) {
        const float v = fast_tanh(acc0[r] + acc1[r] + bv);
        const unsigned short h = f2bf(v);
        const int row = q*4 + r;
        outH[row*KS + cj] = (short)h;
        outL[row*KS + cj] = (short)f2bf(v - bf2f(h));
    }
}

// =====================================================================
// pMLP layer2 fused with pW3 dot (K=256, fragment layout, 16 jtiles).
// =====================================================================
__device__ __forceinline__ void p_l2_dot(
    const short* __restrict__ Wf,
    const float* __restrict__ pb2, const float* __restrict__ pW3,
    const short* __restrict__ inH, const short* __restrict__ inL,
    float* __restrict__ sPpart, int lane, int wid)
{
    const int m = lane & 15, q = lane >> 4;
    const short* wb = Wf + (size_t)wid*8*1024 + lane*8;

    bfx8 bh[8], bl[8];
    #pragma unroll
    for (int kc = 0; kc < 8; ++kc) {
        bh[kc] = *(const bfx8*)(wb + (size_t)kc*1024);
        bl[kc] = *(const bfx8*)(wb + (size_t)kc*1024 + 512);
    }
    f32x4 acc0 = (f32x4){0.f,0.f,0.f,0.f};
    f32x4 acc1 = (f32x4){0.f,0.f,0.f,0.f};

    __syncthreads();

    const short* aph = inH + m*KS + q*8;
    const short* apl = inL + m*KS + q*8;

    #pragma unroll
    for (int kc = 0; kc < 8; ++kc) {
        const bfx8 ah = *(const bfx8*)(aph + kc*32);
        const bfx8 al = *(const bfx8*)(apl + kc*32);
        acc0 = __builtin_amdgcn_mfma_f32_16x16x32_bf16(ah, bh[kc], acc0, 0, 0, 0);
        acc1 = __builtin_amdgcn_mfma_f32_16x16x32_bf16(al, bh[kc], acc1, 0, 0, 0);
        acc1 = __builtin_amdgcn_mfma_f32_16x16x32_bf16(ah, bl[kc], acc1, 0, 0, 0);
    }
    const int cj = wid*16 + m;
    const float bv = pb2[cj];
    const float w3 = pW3[cj];
    float ps[4];
    #pragma unroll
    for (int r = 0; r < 4; ++r)
        ps[r] = fast_tanh(acc0[r] + acc1[r] + bv) * w3;
    #pragma unroll
    for (int mask = 1; mask <= 8; mask <<= 1) {
        #pragma unroll
        for (int r = 0; r < 4; ++r) ps[r] += __shfl_xor(ps[r], mask);
    }
    if (m == 0) {
        #pragma unroll
        for (int r = 0; r < 4; ++r) sPpart[wid*16 + q*4 + r] = ps[r];
    }
}

// =====================================================================
// Layer 3: 16m x 96o, K=256, no act, fp32 out gbuf [e][o] stride XS.
// 6 jtiles on waves 0-5; waves 6-15 pass through the barrier.
// =====================================================================
__device__ __forceinline__ void layer_out(
    const short* __restrict__ Wf, const float* __restrict__ bias,
    const short* __restrict__ inH, const short* __restrict__ inL,
    float* __restrict__ gbuf, int lane, int wid)
{
    const int m = lane & 15, q = lane >> 4;
    bfx8 bh[8], bl[8];
    if (wid < 6) {
        const short* wb = Wf + (size_t)wid*8*1024 + lane*8;
        #pragma unroll
        for (int kc = 0; kc < 8; ++kc) {
            bh[kc] = *(const bfx8*)(wb + (size_t)kc*1024);
            bl[kc] = *(const bfx8*)(wb + (size_t)kc*1024 + 512);
        }
    }
    __syncthreads();
    if (wid < 6) {
        const short* aph = inH + m*KS + q*8;
        const short* apl = inL + m*KS + q*8;
        f32x4 acc0 = (f32x4){0.f,0.f,0.f,0.f};
        f32x4 acc1 = (f32x4){0.f,0.f,0.f,0.f};
        #pragma unroll
        for (int kc = 0; kc < 8; ++kc) {
            const bfx8 ah = *(const bfx8*)(aph + kc*32);
            const bfx8 al = *(const bfx8*)(apl + kc*32);
            acc0 = __builtin_amdgcn_mfma_f32_16x16x32_bf16(ah, bh[kc], acc0, 0, 0, 0);
            acc1 = __builtin_amdgcn_mfma_f32_16x16x32_bf16(al, bh[kc], acc1, 0, 0, 0);
            acc1 = __builtin_amdgcn_mfma_f32_16x16x32_bf16(ah, bl[kc], acc1, 0, 0, 0);
        }
        const int cj = wid*16 + m;
        const float bv = bias[cj];
        #pragma unroll
        for (int r = 0; r < 4; ++r)
            gbuf[(q*4 + r)*XS + cj] = acc0[r] + acc1[r] + bv;
    }
}

// =====================================================================
// Particle / SDE update: 1 thread = 1 particle (tid < 512).
// Position math bit-identical to rounds 1-4 (fp32, contract off, libm).
// dBt value is pre-fetched by the caller (db) to hide HBM latency.
// =====================================================================
__device__ __forceinline__ void particles_step2(
    float2 db, float s2d, float sqdt,
    float* __restrict__ xsF, const float* __restrict__ gbuf,
    short* __restrict__ xH, short* __restrict__ xL,
    float* __restrict__ sP, float* __restrict__ sRun, float* __restrict__ sRel,
    int tid)
{
#pragma clang fp contract(off)
    const int e = tid >> 5;          // 0..15
    const int p = tid & 31;          // particle
    const float runf = sRun[e];

    const float db0 = db.x * sqdt;
    const float db1 = db.y * sqdt;
    const float dp0 = s2d * db0;
    const float dp1 = s2d * db1;
    const float X = xsF[e*XS + 3*p + 0];
    const float Y = xsF[e*XS + 3*p + 1];
    const float Z = xsF[e*XS + 3*p + 2];
    const float zc = fminf(fmaxf(Z, -0.999999f), 0.999999f);
    const float theta = acosf(zc);
    const float phi = atan2f(Y, X);
    const float aa = theta - PIO2F;
    const float ca = cosf(aa), sa = sinf(aa);
    const float cp = cosf(phi), sp = sinf(phi);
    const float th = dp0 + PIO2F;
    const float st = sinf(th);
    const float e0v = st * cosf(dp1) - 1.0f;
    const float e1v = st * sinf(dp1);
    const float e2v = cosf(th);
    const float d0 = cp*ca*e0v - sp*e1v + cp*sa*e2v;
    const float d1 = sp*ca*e0v + cp*e1v + sp*sa*e2v;
    const float d2 = -sa*e0v + ca*e2v;
    float Xn = X + runf*d0;
    float Yn = Y + runf*d1;
    float Zn = Z + runf*d2;
    Zn = (Zn < 0.f) ? -Zn : Zn;
    int   hit   = (Zn < 0.05f) ? 1 : 0;
    float psum  = Xn + Yn + Zn;
    const float g0 = gbuf[e*XS + 3*p + 0];
    const float g1 = gbuf[e*XS + 3*p + 1];
    const float g2 = gbuf[e*XS + 3*p + 2];
    const float r1 = -g0*sp + g1*cp;
    const float r2 = g0*cp*sa + g1*sp*sa + g2*ca;
    float dpsum = (-r2)*dp0 + r1*dp1;

    xsF[e*XS + 3*p + 0] = Xn;
    xsF[e*XS + 3*p + 1] = Yn;
    xsF[e*XS + 3*p + 2] = Zn;
    const float nv[3] = {Xn, Yn, Zn};
    #pragma unroll
    for (int c = 0; c < 3; ++c) {
        const unsigned short h = f2bf(nv[c]);
        xH[e*KS + 3*p + c] = (short)h;
        xL[e*KS + 3*p + c] = (short)f2bf(nv[c] - bf2f(h));
    }
    #pragma unroll
    for (int mask = 1; mask <= 16; mask <<= 1) {
        dpsum += __shfl_xor(dpsum, mask);
        psum  += __shfl_xor(psum, mask);
        hit   |= __shfl_xor(hit, mask);
    }
    if (p == 0) {
        const float pv = sP[e];
        const float rv = runf;
        const float dp = -(0.2f * pv) * 0.01f + dpsum;
        sP[e] = pv + dp * rv;
        const bool rb = rv > 0.5f;
        if (rb && hit) sRel[e] = psum / 96.0f;
        sRun[e] = (rb && !hit) ? 1.0f : 0.0f;
    }
}

__global__ __launch_bounds__(1024, 4)
void sphere_mfma_kernel(
    const float* __restrict__ x0,  const float* __restrict__ dBt,
    const float* __restrict__ Dv,
    const short* __restrict__ pW1f, const float* __restrict__ pb1,
    const short* __restrict__ pW2f, const float* __restrict__ pb2,
    const float* __restrict__ pW3,  const float* __restrict__ pb3,
    const short* __restrict__ gW1f, const float* __restrict__ gb1,
    const short* __restrict__ gW2f, const float* __restrict__ gb2,
    const short* __restrict__ gW3f, const float* __restrict__ gb3,
    float* __restrict__ out)
{
    __shared__ short aH0[16*KS], aL0[16*KS], aH1[16*KS], aL1[16*KS];
    __shared__ float xsF[NE*XS], gbuf[NE*XS];
    __shared__ float sPpart[NWAVE*16];
    __shared__ float sP[NE], sRun[NE], sRel[NE];

    const int tid  = threadIdx.x;
    const int lane = tid & 63, wid = tid >> 6;
    const int b0   = blockIdx.x * NE;

    // x0 -> xsF (fp32) + split-bf16 A buffer
    for (int i = tid; i < NE*96; i += 1024) {
        const int e = i / 96, k = i - e*96;
        const float v = x0[(size_t)b0*96 + i];
        xsF[e*XS + k] = v;
        const unsigned short h = f2bf(v);
        aH0[e*KS + k] = (short)h;
        aL0[e*KS + k] = (short)f2bf(v - bf2f(h));
    }

    // ---- p0 = pMLP(x0), layer2 fused with pW3 dot ----
    layer_hidden<3>(pW1f, pb1, aH0, aL0, aH1, aL1, lane, wid);
    p_l2_dot(pW2f, pb2, pW3, aH1, aL1, sPpart, lane, wid);
    __syncthreads();
    if (tid < NE) {
        float s = pb3[0];
        #pragma unroll
        for (int w = 0; w < NWAVE; ++w) s += sPpart[w*16 + tid];
        sP[tid] = s; sRun[tid] = 1.0f; sRel[tid] = 0.0f;
    }

    const float s2d  = sqrtf(2.0f * Dv[tid & 31]);
    const float sqdt = sqrtf(0.01f);
    const float* dbp = (tid < 512)
        ? dBt + (((size_t)(b0 + (tid >> 5)))*DXP + (tid & 31))*2 : dBt;

    // ---- 100 scan steps, 4 barriers each ----
    for (int t = 0; t < NSTEPS; ++t) {
        layer_hidden<3>(gW1f + (size_t)t*49152,  gb1 + (size_t)t*256,
                        aH0, aL0, aH1, aL1, lane, wid);
        layer_hidden<8>(gW2f + (size_t)t*131072, gb2 + (size_t)t*256,
                        aH1, aL1, aH0, aL0, lane, wid);
        // prefetch this step's noise while layer_out runs
        float2 db = make_float2(0.f, 0.f);
        if (tid < 512) db = *(const float2*)(dbp + (size_t)t*BATCH*DXP*2);
        layer_out(gW3f + (size_t)t*49152, gb3 + (size_t)t*96,
                  aH0, aL0, gbuf, lane, wid);
        __syncthreads();
        if (tid < 512)
            particles_step2(db, s2d, sqdt, xsF, gbuf, aH0, aL0,
                            sP, sRun, sRel, tid);
    }

    // ---- finalize ----
    __syncthreads();
    if (tid < 512) {
        const int e = tid >> 5, tt = tid & 31;
        const int b = b0 + e;
        float s = xsF[e*XS + 3*tt] + xsF[e*XS + 3*tt + 1] + xsF[e*XS + 3*tt + 2];
        #pragma unroll
        for (int mask = 1; mask <= 16; mask <<= 1) s += __shfl_xor(s, mask);
        if (tt == 0) {
            out[2*b] = sP[e];
            float pr = sRel[e];
            if (sRun[e] > 0.5f) pr = s / 96.0f;
            out[2*b + 1] = pr;
        }
    }
}

// =====================================================================
// ===================== FALLBACK (fp32, round-1) ======================
// =====================================================================
#define FNE 16
#define SH 20
#define SX 16

__device__ __forceinline__ void layer256_fb(
    int K, const float* __restrict__ W, const float* __restrict__ bias,
    const float* __restrict__ in_lds, int in_stride,
    float* __restrict__ out_lds, float* __restrict__ wbuf, int tid)
{
    const int jg = tid & 63;
    const int eg = tid >> 6;
    const int j0 = jg << 2;
    const int e0 = eg << 2;
    float acc[4][4];
    #pragma unroll
    for (int ee = 0; ee < 4; ++ee)
        #pragma unroll
        for (int jj = 0; jj < 4; ++jj) acc[ee][jj] = 0.f;
    const int nc = K >> 4;
    const float4* __restrict__ Wv = (const float4*)W;
    float4* wv = (float4*)wbuf;
    float4 pre[4];
    #pragma unroll
    for (int i = 0; i < 4; ++i) pre[i] = Wv[tid + i*256];
    for (int c = 0; c < nc; ++c) {
        __syncthreads();
        #pragma unroll
        for (int i = 0; i < 4; ++i) wv[tid + i*256] = pre[i];
        if (c + 1 < nc) {
            #pragma unroll
            for (int i = 0; i < 4; ++i) pre[i] = Wv[(c+1)*1024 + tid + i*256];
        }
        __syncthreads();
        const float* inb = in_lds + (c << 4) * in_stride + e0;
        #pragma unroll
        for (int kk = 0; kk < 16; ++kk) {
            const float4 a = *(const float4*)(inb + kk * in_stride);
            const float4 w = *(const float4*)(wbuf + kk*256 + j0);
            const float av[4] = {a.x, a.y, a.z, a.w};
            const float wl[4] = {w.x, w.y, w.z, w.w};
            #pragma unroll
            for (int ee = 0; ee < 4; ++ee)
                #pragma unroll
                for (int jj = 0; jj < 4; ++jj)
                    acc[ee][jj] += av[ee] * wl[jj];
        }
    }
    const float4 bb = *(const float4*)(bias + j0);
    const float bv[4] = {bb.x, bb.y, bb.z, bb.w};
    #pragma unroll
    for (int jj = 0; jj < 4; ++jj) {
        float4 v;
        v.x = tanhf(acc[0][jj] + bv[jj]);
        v.y = tanhf(acc[1][jj] + bv[jj]);
        v.z = tanhf(acc[2][jj] + bv[jj]);
        v.w = tanhf(acc[3][jj] + bv[jj]);
        *(float4*)(out_lds + (j0 + jj) * SH + e0) = v;
    }
}

__device__ __forceinline__ void layer3_fb(
    const float* __restrict__ W, const float* __restrict__ bias,
    const float* __restrict__ h2, float* __restrict__ wbuf,
    float* __restrict__ gbuf, int tid)
{
    const int og = tid & 31;
    const int eg = tid >> 5;
    const int o0 = og * 3;
    const int e0 = eg << 1;
    float acc[2][3];
    #pragma unroll
    for (int ee = 0; ee < 2; ++ee)
        #pragma unroll
        for (int oo = 0; oo < 3; ++oo) acc[ee][oo] = 0.f;
    const float2* __restrict__ Wv = (const float2*)W;
    float2* wv2 = (float2*)wbuf;
    float2 pre[3];
    #pragma unroll
    for (int i = 0; i < 3; ++i) pre[i] = Wv[tid + i*256];
    for (int c = 0; c < 16; ++c) {
        __syncthreads();
        #pragma unroll
        for (int i = 0; i < 3; ++i) wv2[tid + i*256] = pre[i];
        if (c + 1 < 16) {
            #pragma unroll
            for (int i = 0; i < 3; ++i) pre[i] = Wv[(c+1)*768 + tid + i*256];
        }
        __syncthreads();
        #pragma unroll
        for (int kk = 0; kk < 16; ++kk) {
            const float2 a = *(const float2*)(h2 + (c*16 + kk)*SH + e0);
            const float* wr = wbuf + kk*96 + o0;
            const float w0 = wr[0], w1 = wr[1], w2 = wr[2];
            acc[0][0] += a.x*w0; acc[0][1] += a.x*w1; acc[0][2] += a.x*w2;
            acc[1][0] += a.y*w0; acc[1][1] += a.y*w1; acc[1][2] += a.y*w2;
        }
    }
    __syncthreads();
    #pragma unroll
    for (int ee = 0; ee < 2; ++ee)
        #pragma unroll
        for (int oo = 0; oo < 3; ++oo)
            gbuf[(e0 + ee)*96 + o0 + oo] = acc[ee][oo] + bias[o0 + oo];
    __syncthreads();
}

__device__ __forceinline__ void particles_step_fb(
    int t, int b0, const float* __restrict__ dBt,
    float s2d0, float s2d1, float sqdt,
    float* __restrict__ xsT, const float* __restrict__ gbuf,
    float* __restrict__ sP, float* __restrict__ sRun, float* __restrict__ sRel,
    int tid)
{
#pragma clang fp contract(off)
    const int e  = tid >> 4;
    const int tt = tid & 15;
    const int b  = b0 + e;
    const float runf = sRun[e];
    float dpsum = 0.f, psum = 0.f;
    int hit = 0;
    #pragma unroll
    for (int pp = 0; pp < 2; ++pp) {
        const int p = tt + (pp << 4);
        const float s2d = pp ? s2d1 : s2d0;
        const float2 db = *(const float2*)(dBt + (((size_t)t*BATCH + b)*DXP + p)*2);
        const float db0 = db.x * sqdt;
        const float db1 = db.y * sqdt;
        const float dp0 = s2d * db0;
        const float dp1 = s2d * db1;
        const float X = xsT[(3*p + 0)*SX + e];
        const float Y = xsT[(3*p + 1)*SX + e];
        const float Z = xsT[(3*p + 2)*SX + e];
        const float zc = fminf(fmaxf(Z, -0.999999f), 0.999999f);
        const float theta = acosf(zc);
        const float phi = atan2f(Y, X);
        const float aa = theta - PIO2F;
        const float ca = cosf(aa), sa = sinf(aa);
        const float cp = cosf(phi), sp = sinf(phi);
        const float th = dp0 + PIO2F;
        const float st = sinf(th);
        const float e0v = st * cosf(dp1) - 1.0f;
        const float e1v = st * sinf(dp1);
        const float e2v = cosf(th);
        const float d0 = cp*ca*e0v - sp*e1v + cp*sa*e2v;
        const float d1 = sp*ca*e0v + cp*e1v + sp*sa*e2v;
        const float d2 = -sa*e0v + ca*e2v;
        float Xn = X + runf*d0;
        float Yn = Y + runf*d1;
        float Zn = Z + runf*d2;
        Zn = (Zn < 0.f) ? -Zn : Zn;
        hit |= (Zn < 0.05f) ? 1 : 0;
        psum += Xn + Yn + Zn;
        const float g0 = gbuf[e*96 + 3*p + 0];
        const float g1 = gbuf[e*96 + 3*p + 1];
        const float g2 = gbuf[e*96 + 3*p + 2];
        const float r1 = -g0*sp + g1*cp;
        const float r2 = g0*cp*sa + g1*sp*sa + g2*ca;
        dpsum += (-r2)*dp0 + r1*dp1;
        xsT[(3*p + 0)*SX + e] = Xn;
        xsT[(3*p + 1)*SX + e] = Yn;
        xsT[(3*p + 2)*SX + e] = Zn;
    }
    #pragma unroll
    for (int m = 1; m <= 8; m <<= 1) {
        dpsum += __shfl_xor(dpsum, m);
        psum  += __shfl_xor(psum, m);
        hit   |= __shfl_xor(hit, m);
    }
    if (tt == 0) {
        const float pv = sP[e];
        const float rv = sRun[e];
        const float dp = -(0.2f * pv) * 0.01f + dpsum;
        sP[e] = pv + dp * rv;
        const bool rb = rv > 0.5f;
        if (rb && hit) sRel[e] = psum / 96.0f;
        sRun[e] = (rb && !hit) ? 1.0f : 0.0f;
    }
}

__global__ __launch_bounds__(256)
void sphere_ibsde_kernel_fb(
    const float* __restrict__ x0,  const float* __restrict__ dBt,
    const float* __restrict__ Dv,
    const float* __restrict__ pW1, const float* __restrict__ pb1,
    const float* __restrict__ pW2, const float* __restrict__ pb2,
    const float* __restrict__ pW3, const float* __restrict__ pb3,
    const float* __restrict__ gW1, const float* __restrict__ gb1,
    const float* __restrict__ gW2, const float* __restrict__ gb2,
    const float* __restrict__ gW3, const float* __restrict__ gb3,
    float* __restrict__ out)
{
    __shared__ float xsT[96 * SX];
    __shared__ float h1T[256 * SH];
    __shared__ float h2T[256 * SH];
    __shared__ float wbuf[16 * 256];
    __shared__ float sP[FNE], sRun[FNE], sRel[FNE];

    const int tid = threadIdx.x;
    const int b0 = blockIdx.x * FNE;

    #pragma unroll
    for (int i = 0; i < 6; ++i) {
        const int f = tid + i*256;
        const int e = f / 96, k = f - e*96;
        xsT[k*SX + e] = x0[(size_t)b0*96 + f];
    }

    layer256_fb(96,  pW1, pb1, xsT, SX, h1T, wbuf, tid);
    layer256_fb(256, pW2, pb2, h1T, SH, h2T, wbuf, tid);
    __syncthreads();
    {
        const int e = tid >> 4, tt = tid & 15;
        float s = 0.f;
        #pragma unroll
        for (int i = 0; i < 16; ++i) {
            const int k = tt + (i << 4);
            s += h2T[k*SH + e] * pW3[k];
        }
        #pragma unroll
        for (int m = 1; m <= 8; m <<= 1) s += __shfl_xor(s, m);
        if (tt == 0) { sP[e] = s + pb3[0]; sRun[e] = 1.0f; sRel[e] = 0.0f; }
    }

    const int ttc = tid & 15;
    const float s2d0 = sqrtf(2.0f * Dv[ttc]);
    const float s2d1 = sqrtf(2.0f * Dv[ttc + 16]);
    const float sqdt = sqrtf(0.01f);

    for (int t = 0; t < NSTEPS; ++t) {
        layer256_fb(96,  gW1 + (size_t)t*96*256,  gb1 + (size_t)t*256, xsT, SX, h1T, wbuf, tid);
        layer256_fb(256, gW2 + (size_t)t*256*256, gb2 + (size_t)t*256, h1T, SH, h2T, wbuf, tid);
        layer3_fb(gW3 + (size_t)t*256*96, gb3 + (size_t)t*96, h2T, wbuf, wbuf, tid);
        particles_step_fb(t, b0, dBt, s2d0, s2d1, sqdt, xsT, wbuf, sP, sRun, sRel, tid);
    }

    __syncthreads();
    {
        const int e = tid >> 4, tt = tid & 15;
        const int b = b0 + e;
        float s = 0.f;
        #pragma unroll
        for (int i = 0; i < 6; ++i) s += xsT[(tt*6 + i)*SX + e];
        #pragma unroll
        for (int m = 1; m <= 8; m <<= 1) s += __shfl_xor(s, m);
        if (tt == 0) {
            out[2*b] = sP[e];
            float pr = sRel[e];
            if (sRun[e] > 0.5f) pr = s / 96.0f;
            out[2*b + 1] = pr;
        }
    }
}

// =====================================================================
extern "C" void kernel_launch(void* const* d_in, const int* in_sizes, int n_in,
                              void* d_out, int out_size, void* d_ws, size_t ws_size,
                              hipStream_t stream)
{
    const float* x0  = (const float*)d_in[0];
    const float* dBt = (const float*)d_in[1];
    const float* Dv  = (const float*)d_in[2];
    const float* pW1 = (const float*)d_in[3];
    const float* pb1 = (const float*)d_in[4];
    const float* pW2 = (const float*)d_in[5];
    const float* pb2 = (const float*)d_in[6];
    const float* pW3 = (const float*)d_in[7];
    const float* pb3 = (const float*)d_in[8];
    const float* gW1 = (const float*)d_in[9];
    const float* gb1 = (const float*)d_in[10];
    const float* gW2 = (const float*)d_in[11];
    const float* gb2 = (const float*)d_in[12];
    const float* gW3 = (const float*)d_in[13];
    const float* gb3 = (const float*)d_in[14];
    float* out = (float*)d_out;

    // fragment-layout sizes in shorts
    const size_t A1 = (size_t)NSTEPS * 16 * 3 * 1024;
    const size_t A2 = (size_t)NSTEPS * 16 * 8 * 1024;
    const size_t A3 = (size_t)NSTEPS *  6 * 8 * 1024;
    const size_t P1 = (size_t)16 * 3 * 1024;
    const size_t P2 = (size_t)16 * 8 * 1024;
    const size_t total_elems = A1 + A2 + A3 + P1 + P2;

    if (ws_size >= total_elems * sizeof(short)) {
        short* p = (short*)d_ws;
        short* gW1f = p;            p += A1;
        short* gW2f = p;            p += A2;
        short* gW3f = p;            p += A3;
        short* pW1f = p;            p += P1;
        short* pW2f = p;            p += P2;

        // grids: one block per (t, kc, q)
        prep_frag_n256<<<dim3(NSTEPS*3*4), dim3(256), 0, stream>>>(gW1, gW1f, 96);
        prep_frag_n256<<<dim3(NSTEPS*8*4), dim3(256), 0, stream>>>(gW2, gW2f, 256);
        prep_frag_n96 <<<dim3(NSTEPS*8*4), dim3(128), 0, stream>>>(gW3, gW3f);
        prep_frag_n256<<<dim3(3*4),        dim3(256), 0, stream>>>(pW1, pW1f, 96);
        prep_frag_n256<<<dim3(8*4),        dim3(256), 0, stream>>>(pW2, pW2f, 256);

        sphere_mfma_kernel<<<dim3(BATCH / NE), dim3(1024), 0, stream>>>(
            x0, dBt, Dv,
            pW1f, pb1, pW2f, pb2, pW3, pb3,
            gW1f, gb1, gW2f, gb2, gW3f, gb3, out);
    } else {
        sphere_ibsde_kernel_fb<<<dim3(BATCH / FNE), dim3(256), 0, stream>>>(
            x0, dBt, Dv, pW1, pb1, pW2, pb2, pW3, pb3,
            gW1, gb1, gW2, gb2, gW3, gb3, out);
    }
}

// Round 6
// 935.303 us; speedup vs baseline: 2.7919x; 1.0429x over previous
//
#include <hip/hip_runtime.h>
#include <cstddef>

typedef short bfx8 __attribute__((ext_vector_type(8)));
typedef float f32x4 __attribute__((ext_vector_type(4)));

#define BATCH   4096
#define DXP     32
#define NSTEPS  100
#define NE      16      // batch elements per block (full 16-row MFMA tiles)
#define NWAVE   16      // waves per block (block = 1024)
#define KS      264     // A-buffer row stride in bf16 elems
#define XS      100     // xsF/gbuf row stride in floats
#define PIO2F   1.57079632679489662f

__device__ __forceinline__ unsigned short f2bf(float v){
    unsigned u = __float_as_uint(v);
    u += 0x7FFFu + ((u >> 16) & 1u);          // RNE
    return (unsigned short)(u >> 16);
}
__device__ __forceinline__ float bf2f(unsigned short h){
    return __uint_as_float(((unsigned)h) << 16);
}
// truncation split: hi = top 16 bits (exact residual), lo = RNE(v - hi).
// Representation error ~2^-17 rel — far under budget; ~4 VALU cheaper than RNE-hi.
__device__ __forceinline__ void split_tr(float v, short& hi, short& lo){
    const unsigned u = __float_as_uint(v);
    hi = (short)(u >> 16);
    lo = (short)f2bf(v - __uint_as_float(u & 0xFFFF0000u));
}
// fast tanh: feeds only the smooth p-path; ~1e-6 abs err vs 4e-2 budget.
__device__ __forceinline__ float fast_tanh(float x){
    const float e2 = __expf(2.0f * x);
    return 1.0f - __fdividef(2.0f, e2 + 1.0f);
}

// =====================================================================
// Prep: W [T][K][N] fp32 -> fragment-major split-bf16:
//   out[((t*NJ + jt)*KC + kc)*1024 + hl*512 + (q*16+m)*8 + i]
//   n = jt*16 + m, k = kc*32 + q*8 + i.
// =====================================================================
__global__ __launch_bounds__(256)
void prep_frag_n256(const float* __restrict__ in, short* __restrict__ out, int K)
{
    const int KC = K >> 5;
    int b = blockIdx.x;                 // t*KC*4 + kc*4 + q
    const int q = b & 3; b >>= 2;
    const int kc = b % KC, t = b / KC;
    const int n = threadIdx.x;
    const int jt = n >> 4, m = n & 15;
    bfx8 hv, lv;
    #pragma unroll
    for (int i = 0; i < 8; ++i) {
        const int k = kc*32 + q*8 + i;
        const float v = in[((size_t)t*K + k)*256 + n];
        const unsigned short h = f2bf(v);
        hv[i] = (short)h;
        lv[i] = (short)f2bf(v - bf2f(h));
    }
    const size_t base = ((size_t)(t*16 + jt)*KC + kc)*1024 + (q*16 + m)*8;
    *(bfx8*)(out + base)       = hv;
    *(bfx8*)(out + base + 512) = lv;
}

// N=96 (layer-3 weights), K=256, NJ=6. One block per (t,kc,q).
__global__ __launch_bounds__(128)
void prep_frag_n96(const float* __restrict__ in, short* __restrict__ out)
{
    int b = blockIdx.x;                 // t*32 + kc*4 + q
    const int q = b & 3; b >>= 2;
    const int kc = b & 7, t = b >> 3;
    const int n = threadIdx.x;
    if (n >= 96) return;
    const int jt = n >> 4, m = n & 15;
    bfx8 hv, lv;
    #pragma unroll
    for (int i = 0; i < 8; ++i) {
        const int k = kc*32 + q*8 + i;
        const float v = in[((size_t)t*256 + k)*96 + n];
        const unsigned short h = f2bf(v);
        hv[i] = (short)h;
        lv[i] = (short)f2bf(v - bf2f(h));
    }
    const size_t base = ((size_t)(t*6 + jt)*8 + kc)*1024 + (q*16 + m)*8;
    *(bfx8*)(out + base)       = hv;
    *(bfx8*)(out + base + 512) = lv;
}

// =====================================================================
// Hidden layer: 16m x 256j, K = KC*32, fast-tanh, trunc-split out.
// Wave w owns j-tile w. Full B preload before the barrier.
// =====================================================================
template<int KC>
__device__ __forceinline__ void layer_hidden(
    const short* __restrict__ Wf, const float* __restrict__ bias,
    const short* __restrict__ inH, const short* __restrict__ inL,
    short* __restrict__ outH, short* __restrict__ outL,
    int lane, int wid)
{
    const int m = lane & 15, q = lane >> 4;
    const short* wb = Wf + (size_t)wid*KC*1024 + lane*8;

    bfx8 bh[KC], bl[KC];
    #pragma unroll
    for (int kc = 0; kc < KC; ++kc) {
        bh[kc] = *(const bfx8*)(wb + (size_t)kc*1024);
        bl[kc] = *(const bfx8*)(wb + (size_t)kc*1024 + 512);
    }
    f32x4 acc0 = (f32x4){0.f,0.f,0.f,0.f};
    f32x4 acc1 = (f32x4){0.f,0.f,0.f,0.f};

    __syncthreads();   // in-buffer written; out-buffer's prior readers done

    const short* aph = inH + m*KS + q*8;
    const short* apl = inL + m*KS + q*8;

    #pragma unroll
    for (int kc = 0; kc < KC; ++kc) {
        const bfx8 ah = *(const bfx8*)(aph + kc*32);
        const bfx8 al = *(const bfx8*)(apl + kc*32);
        acc0 = __builtin_amdgcn_mfma_f32_16x16x32_bf16(ah, bh[kc], acc0, 0, 0, 0);
        acc1 = __builtin_amdgcn_mfma_f32_16x16x32_bf16(al, bh[kc], acc1, 0, 0, 0);
        acc1 = __builtin_amdgcn_mfma_f32_16x16x32_bf16(ah, bl[kc], acc1, 0, 0, 0);
    }
    const int cj = wid*16 + m;
    const float bv = bias[cj];
    #pragma unroll
    for (int r = 0; r < 4; ++r) {
        const float v = fast_tanh(acc0[r] + acc1[r] + bv);
        short h, l; split_tr(v, h, l);
        const int row = q*4 + r;
        outH[row*KS + cj] = h;
        outL[row*KS + cj] = l;
    }
}

// =====================================================================
// pMLP layer2 fused with pW3 dot (K=256, fragment layout, 16 jtiles).
// =====================================================================
__device__ __forceinline__ void p_l2_dot(
    const short* __restrict__ Wf,
    const float* __restrict__ pb2, const float* __restrict__ pW3,
    const short* __restrict__ inH, const short* __restrict__ inL,
    float* __restrict__ sPpart, int lane, int wid)
{
    const int m = lane & 15, q = lane >> 4;
    const short* wb = Wf + (size_t)wid*8*1024 + lane*8;

    bfx8 bh[8], bl[8];
    #pragma unroll
    for (int kc = 0; kc < 8; ++kc) {
        bh[kc] = *(const bfx8*)(wb + (size_t)kc*1024);
        bl[kc] = *(const bfx8*)(wb + (size_t)kc*1024 + 512);
    }
    f32x4 acc0 = (f32x4){0.f,0.f,0.f,0.f};
    f32x4 acc1 = (f32x4){0.f,0.f,0.f,0.f};

    __syncthreads();

    const short* aph = inH + m*KS + q*8;
    const short* apl = inL + m*KS + q*8;

    #pragma unroll
    for (int kc = 0; kc < 8; ++kc) {
        const bfx8 ah = *(const bfx8*)(aph + kc*32);
        const bfx8 al = *(const bfx8*)(apl + kc*32);
        acc0 = __builtin_amdgcn_mfma_f32_16x16x32_bf16(ah, bh[kc], acc0, 0, 0, 0);
        acc1 = __builtin_amdgcn_mfma_f32_16x16x32_bf16(al, bh[kc], acc1, 0, 0, 0);
        acc1 = __builtin_amdgcn_mfma_f32_16x16x32_bf16(ah, bl[kc], acc1, 0, 0, 0);
    }
    const int cj = wid*16 + m;
    const float bv = pb2[cj];
    const float w3 = pW3[cj];
    float ps[4];
    #pragma unroll
    for (int r = 0; r < 4; ++r)
        ps[r] = fast_tanh(acc0[r] + acc1[r] + bv) * w3;
    #pragma unroll
    for (int mask = 1; mask <= 8; mask <<= 1) {
        #pragma unroll
        for (int r = 0; r < 4; ++r) ps[r] += __shfl_xor(ps[r], mask);
    }
    if (m == 0) {
        #pragma unroll
        for (int r = 0; r < 4; ++r) sPpart[wid*16 + q*4 + r] = ps[r];
    }
}

// =====================================================================
// Layer 3: 16m x 96o, K=256, no act, fp32 out gbuf [e][o] stride XS.
// =====================================================================
__device__ __forceinline__ void layer_out(
    const short* __restrict__ Wf, const float* __restrict__ bias,
    const short* __restrict__ inH, const short* __restrict__ inL,
    float* __restrict__ gbuf, int lane, int wid)
{
    const int m = lane & 15, q = lane >> 4;
    bfx8 bh[8], bl[8];
    if (wid < 6) {
        const short* wb = Wf + (size_t)wid*8*1024 + lane*8;
        #pragma unroll
        for (int kc = 0; kc < 8; ++kc) {
            bh[kc] = *(const bfx8*)(wb + (size_t)kc*1024);
            bl[kc] = *(const bfx8*)(wb + (size_t)kc*1024 + 512);
        }
    }
    __syncthreads();
    if (wid < 6) {
        const short* aph = inH + m*KS + q*8;
        const short* apl = inL + m*KS + q*8;
        f32x4 acc0 = (f32x4){0.f,0.f,0.f,0.f};
        f32x4 acc1 = (f32x4){0.f,0.f,0.f,0.f};
        #pragma unroll
        for (int kc = 0; kc < 8; ++kc) {
            const bfx8 ah = *(const bfx8*)(aph + kc*32);
            const bfx8 al = *(const bfx8*)(apl + kc*32);
            acc0 = __builtin_amdgcn_mfma_f32_16x16x32_bf16(ah, bh[kc], acc0, 0, 0, 0);
            acc1 = __builtin_amdgcn_mfma_f32_16x16x32_bf16(al, bh[kc], acc1, 0, 0, 0);
            acc1 = __builtin_amdgcn_mfma_f32_16x16x32_bf16(ah, bl[kc], acc1, 0, 0, 0);
        }
        const int cj = wid*16 + m;
        const float bv = bias[cj];
        #pragma unroll
        for (int r = 0; r < 4; ++r)
            gbuf[(q*4 + r)*XS + cj] = acc0[r] + acc1[r] + bv;
    }
}

// =====================================================================
// Particle / SDE update: 1 thread = 1 particle (tid < 512).
// Trig via algebraic identities (ulp-class deviation from libm path):
//   cos(theta-pi/2)=sin(theta)=sqrt(1-z^2); sin(theta-pi/2)=-z
//   cos(phi)=X/r, sin(phi)=Y/r; sin(dp0+pi/2)=cos(dp0); cos(dp0+pi/2)=-sin(dp0)
// =====================================================================
__device__ __forceinline__ void particles_step2(
    float2 db, float s2d, float sqdt,
    float* __restrict__ xsF, const float* __restrict__ gbuf,
    short* __restrict__ xH, short* __restrict__ xL,
    float* __restrict__ sP, float* __restrict__ sRun, float* __restrict__ sRel,
    int tid)
{
#pragma clang fp contract(off)
    const int e = tid >> 5;          // 0..15
    const int p = tid & 31;          // particle
    const float runf = sRun[e];

    const float db0 = db.x * sqdt;
    const float db1 = db.y * sqdt;
    const float dp0 = s2d * db0;
    const float dp1 = s2d * db1;
    const float X = xsF[e*XS + 3*p + 0];
    const float Y = xsF[e*XS + 3*p + 1];
    const float Z = xsF[e*XS + 3*p + 2];
    const float zc = fminf(fmaxf(Z, -0.999999f), 0.999999f);
    const float ca = sqrtf(fmaxf(1.0f - zc*zc, 0.0f));   // sin(theta)
    const float sa = -zc;                                 // -cos(theta)
    const float r2 = X*X + Y*Y;
    const float rinv = rsqrtf(fmaxf(r2, 1e-30f));
    const float cp = X * rinv;
    const float sp = Y * rinv;
    const float c0 = cosf(dp0), s0 = sinf(dp0);
    const float c1 = cosf(dp1), s1 = sinf(dp1);
    const float e0v = c0 * c1 - 1.0f;
    const float e1v = c0 * s1;
    const float e2v = -s0;
    const float d0 = cp*ca*e0v - sp*e1v + cp*sa*e2v;
    const float d1 = sp*ca*e0v + cp*e1v + sp*sa*e2v;
    const float d2 = -sa*e0v + ca*e2v;
    float Xn = X + runf*d0;
    float Yn = Y + runf*d1;
    float Zn = Z + runf*d2;
    Zn = (Zn < 0.f) ? -Zn : Zn;
    int   hit   = (Zn < 0.05f) ? 1 : 0;
    float psum  = Xn + Yn + Zn;
    const float g0 = gbuf[e*XS + 3*p + 0];
    const float g1 = gbuf[e*XS + 3*p + 1];
    const float g2 = gbuf[e*XS + 3*p + 2];
    const float r1 = -g0*sp + g1*cp;
    const float rr2 = g0*cp*sa + g1*sp*sa + g2*ca;
    float dpsum = (-rr2)*dp0 + r1*dp1;

    xsF[e*XS + 3*p + 0] = Xn;
    xsF[e*XS + 3*p + 1] = Yn;
    xsF[e*XS + 3*p + 2] = Zn;
    const float nv[3] = {Xn, Yn, Zn};
    #pragma unroll
    for (int c = 0; c < 3; ++c) {
        short h, l; split_tr(nv[c], h, l);
        xH[e*KS + 3*p + c] = h;
        xL[e*KS + 3*p + c] = l;
    }
    #pragma unroll
    for (int mask = 1; mask <= 16; mask <<= 1) {
        dpsum += __shfl_xor(dpsum, mask);
        psum  += __shfl_xor(psum, mask);
        hit   |= __shfl_xor(hit, mask);
    }
    if (p == 0) {
        const float pv = sP[e];
        const float rv = runf;
        const float dp = -(0.2f * pv) * 0.01f + dpsum;
        sP[e] = pv + dp * rv;
        const bool rb = rv > 0.5f;
        if (rb && hit) sRel[e] = psum / 96.0f;
        sRun[e] = (rb && !hit) ? 1.0f : 0.0f;
    }
}

__global__ __launch_bounds__(1024, 4)
void sphere_mfma_kernel(
    const float* __restrict__ x0,  const float* __restrict__ dBt,
    const float* __restrict__ Dv,
    const short* __restrict__ pW1f, const float* __restrict__ pb1,
    const short* __restrict__ pW2f, const float* __restrict__ pb2,
    const float* __restrict__ pW3,  const float* __restrict__ pb3,
    const short* __restrict__ gW1f, const float* __restrict__ gb1,
    const short* __restrict__ gW2f, const float* __restrict__ gb2,
    const short* __restrict__ gW3f, const float* __restrict__ gb3,
    float* __restrict__ out)
{
    __shared__ short aH0[16*KS], aL0[16*KS], aH1[16*KS], aL1[16*KS];
    __shared__ float xsF[NE*XS], gbuf[NE*XS];
    __shared__ float sPpart[NWAVE*16];
    __shared__ float sP[NE], sRun[NE], sRel[NE];

    const int tid  = threadIdx.x;
    const int lane = tid & 63, wid = tid >> 6;
    const int b0   = blockIdx.x * NE;

    // x0 -> xsF (fp32) + split-bf16 A buffer
    for (int i = tid; i < NE*96; i += 1024) {
        const int e = i / 96, k = i - e*96;
        const float v = x0[(size_t)b0*96 + i];
        xsF[e*XS + k] = v;
        short h, l; split_tr(v, h, l);
        aH0[e*KS + k] = h;
        aL0[e*KS + k] = l;
    }

    // ---- p0 = pMLP(x0), layer2 fused with pW3 dot ----
    layer_hidden<3>(pW1f, pb1, aH0, aL0, aH1, aL1, lane, wid);
    p_l2_dot(pW2f, pb2, pW3, aH1, aL1, sPpart, lane, wid);
    __syncthreads();
    if (tid < NE) {
        float s = pb3[0];
        #pragma unroll
        for (int w = 0; w < NWAVE; ++w) s += sPpart[w*16 + tid];
        sP[tid] = s; sRun[tid] = 1.0f; sRel[tid] = 0.0f;
    }

    const float s2d  = sqrtf(2.0f * Dv[tid & 31]);
    const float sqdt = sqrtf(0.01f);
    const float* dbp = (tid < 512)
        ? dBt + (((size_t)(b0 + (tid >> 5)))*DXP + (tid & 31))*2 : dBt;

    // ---- 100 scan steps, 4 barriers each ----
    for (int t = 0; t < NSTEPS; ++t) {
        layer_hidden<3>(gW1f + (size_t)t*49152,  gb1 + (size_t)t*256,
                        aH0, aL0, aH1, aL1, lane, wid);
        layer_hidden<8>(gW2f + (size_t)t*131072, gb2 + (size_t)t*256,
                        aH1, aL1, aH0, aL0, lane, wid);
        // prefetch this step's noise while layer_out runs
        float2 db = make_float2(0.f, 0.f);
        if (tid < 512) db = *(const float2*)(dbp + (size_t)t*BATCH*DXP*2);
        layer_out(gW3f + (size_t)t*49152, gb3 + (size_t)t*96,
                  aH0, aL0, gbuf, lane, wid);
        __syncthreads();
        if (tid < 512)
            particles_step2(db, s2d, sqdt, xsF, gbuf, aH0, aL0,
                            sP, sRun, sRel, tid);
    }

    // ---- finalize ----
    __syncthreads();
    if (tid < 512) {
        const int e = tid >> 5, tt = tid & 31;
        const int b = b0 + e;
        float s = xsF[e*XS + 3*tt] + xsF[e*XS + 3*tt + 1] + xsF[e*XS + 3*tt + 2];
        #pragma unroll
        for (int mask = 1; mask <= 16; mask <<= 1) s += __shfl_xor(s, mask);
        if (tt == 0) {
            out[2*b] = sP[e];
            float pr = sRel[e];
            if (sRun[e] > 0.5f) pr = s / 96.0f;
            out[2*b + 1] = pr;
        }
    }
}

// =====================================================================
// ===================== FALLBACK (fp32, round-1) ======================
// =====================================================================
#define FNE 16
#define SH 20
#define SX 16

__device__ __forceinline__ void layer256_fb(
    int K, const float* __restrict__ W, const float* __restrict__ bias,
    const float* __restrict__ in_lds, int in_stride,
    float* __restrict__ out_lds, float* __restrict__ wbuf, int tid)
{
    const int jg = tid & 63;
    const int eg = tid >> 6;
    const int j0 = jg << 2;
    const int e0 = eg << 2;
    float acc[4][4];
    #pragma unroll
    for (int ee = 0; ee < 4; ++ee)
        #pragma unroll
        for (int jj = 0; jj < 4; ++jj) acc[ee][jj] = 0.f;
    const int nc = K >> 4;
    const float4* __restrict__ Wv = (const float4*)W;
    float4* wv = (float4*)wbuf;
    float4 pre[4];
    #pragma unroll
    for (int i = 0; i < 4; ++i) pre[i] = Wv[tid + i*256];
    for (int c = 0; c < nc; ++c) {
        __syncthreads();
        #pragma unroll
        for (int i = 0; i < 4; ++i) wv[tid + i*256] = pre[i];
        if (c + 1 < nc) {
            #pragma unroll
            for (int i = 0; i < 4; ++i) pre[i] = Wv[(c+1)*1024 + tid + i*256];
        }
        __syncthreads();
        const float* inb = in_lds + (c << 4) * in_stride + e0;
        #pragma unroll
        for (int kk = 0; kk < 16; ++kk) {
            const float4 a = *(const float4*)(inb + kk * in_stride);
            const float4 w = *(const float4*)(wbuf + kk*256 + j0);
            const float av[4] = {a.x, a.y, a.z, a.w};
            const float wl[4] = {w.x, w.y, w.z, w.w};
            #pragma unroll
            for (int ee = 0; ee < 4; ++ee)
                #pragma unroll
                for (int jj = 0; jj < 4; ++jj)
                    acc[ee][jj] += av[ee] * wl[jj];
        }
    }
    const float4 bb = *(const float4*)(bias + j0);
    const float bv[4] = {bb.x, bb.y, bb.z, bb.w};
    #pragma unroll
    for (int jj = 0; jj < 4; ++jj) {
        float4 v;
        v.x = tanhf(acc[0][jj] + bv[jj]);
        v.y = tanhf(acc[1][jj] + bv[jj]);
        v.z = tanhf(acc[2][jj] + bv[jj]);
        v.w = tanhf(acc[3][jj] + bv[jj]);
        *(float4*)(out_lds + (j0 + jj) * SH + e0) = v;
    }
}

__device__ __forceinline__ void layer3_fb(
    const float* __restrict__ W, const float* __restrict__ bias,
    const float* __restrict__ h2, float* __restrict__ wbuf,
    float* __restrict__ gbuf, int tid)
{
    const int og = tid & 31;
    const int eg = tid >> 5;
    const int o0 = og * 3;
    const int e0 = eg << 1;
    float acc[2][3];
    #pragma unroll
    for (int ee = 0; ee < 2; ++ee)
        #pragma unroll
        for (int oo = 0; oo < 3; ++oo) acc[ee][oo] = 0.f;
    const float2* __restrict__ Wv = (const float2*)W;
    float2* wv2 = (float2*)wbuf;
    float2 pre[3];
    #pragma unroll
    for (int i = 0; i < 3; ++i) pre[i] = Wv[tid + i*256];
    for (int c = 0; c < 16; ++c) {
        __syncthreads();
        #pragma unroll
        for (int i = 0; i < 3; ++i) wv2[tid + i*256] = pre[i];
        if (c + 1 < 16) {
            #pragma unroll
            for (int i = 0; i < 3; ++i) pre[i] = Wv[(c+1)*768 + tid + i*256];
        }
        __syncthreads();
        #pragma unroll
        for (int kk = 0; kk < 16; ++kk) {
            const float2 a = *(const float2*)(h2 + (c*16 + kk)*SH + e0);
            const float* wr = wbuf + kk*96 + o0;
            const float w0 = wr[0], w1 = wr[1], w2 = wr[2];
            acc[0][0] += a.x*w0; acc[0][1] += a.x*w1; acc[0][2] += a.x*w2;
            acc[1][0] += a.y*w0; acc[1][1] += a.y*w1; acc[1][2] += a.y*w2;
        }
    }
    __syncthreads();
    #pragma unroll
    for (int ee = 0; ee < 2; ++ee)
        #pragma unroll
        for (int oo = 0; oo < 3; ++oo)
            gbuf[(e0 + ee)*96 + o0 + oo] = acc[ee][oo] + bias[o0 + oo];
    __syncthreads();
}

__device__ __forceinline__ void particles_step_fb(
    int t, int b0, const float* __restrict__ dBt,
    float s2d0, float s2d1, float sqdt,
    float* __restrict__ xsT, const float* __restrict__ gbuf,
    float* __restrict__ sP, float* __restrict__ sRun, float* __restrict__ sRel,
    int tid)
{
#pragma clang fp contract(off)
    const int e  = tid >> 4;
    const int tt = tid & 15;
    const int b  = b0 + e;
    const float runf = sRun[e];
    float dpsum = 0.f, psum = 0.f;
    int hit = 0;
    #pragma unroll
    for (int pp = 0; pp < 2; ++pp) {
        const int p = tt + (pp << 4);
        const float s2d = pp ? s2d1 : s2d0;
        const float2 db = *(const float2*)(dBt + (((size_t)t*BATCH + b)*DXP + p)*2);
        const float db0 = db.x * sqdt;
        const float db1 = db.y * sqdt;
        const float dp0 = s2d * db0;
        const float dp1 = s2d * db1;
        const float X = xsT[(3*p + 0)*SX + e];
        const float Y = xsT[(3*p + 1)*SX + e];
        const float Z = xsT[(3*p + 2)*SX + e];
        const float zc = fminf(fmaxf(Z, -0.999999f), 0.999999f);
        const float theta = acosf(zc);
        const float phi = atan2f(Y, X);
        const float aa = theta - PIO2F;
        const float ca = cosf(aa), sa = sinf(aa);
        const float cp = cosf(phi), sp = sinf(phi);
        const float th = dp0 + PIO2F;
        const float st = sinf(th);
        const float e0v = st * cosf(dp1) - 1.0f;
        const float e1v = st * sinf(dp1);
        const float e2v = cosf(th);
        const float d0 = cp*ca*e0v - sp*e1v + cp*sa*e2v;
        const float d1 = sp*ca*e0v + cp*e1v + sp*sa*e2v;
        const float d2 = -sa*e0v + ca*e2v;
        float Xn = X + runf*d0;
        float Yn = Y + runf*d1;
        float Zn = Z + runf*d2;
        Zn = (Zn < 0.f) ? -Zn : Zn;
        hit |= (Zn < 0.05f) ? 1 : 0;
        psum += Xn + Yn + Zn;
        const float g0 = gbuf[e*96 + 3*p + 0];
        const float g1 = gbuf[e*96 + 3*p + 1];
        const float g2 = gbuf[e*96 + 3*p + 2];
        const float r1 = -g0*sp + g1*cp;
        const float r2 = g0*cp*sa + g1*sp*sa + g2*ca;
        dpsum += (-r2)*dp0 + r1*dp1;
        xsT[(3*p + 0)*SX + e] = Xn;
        xsT[(3*p + 1)*SX + e] = Yn;
        xsT[(3*p + 2)*SX + e] = Zn;
    }
    #pragma unroll
    for (int m = 1; m <= 8; m <<= 1) {
        dpsum += __shfl_xor(dpsum, m);
        psum  += __shfl_xor(psum, m);
        hit   |= __shfl_xor(hit, m);
    }
    if (tt == 0) {
        const float pv = sP[e];
        const float rv = sRun[e];
        const float dp = -(0.2f * pv) * 0.01f + dpsum;
        sP[e] = pv + dp * rv;
        const bool rb = rv > 0.5f;
        if (rb && hit) sRel[e] = psum / 96.0f;
        sRun[e] = (rb && !hit) ? 1.0f : 0.0f;
    }
}

__global__ __launch_bounds__(256)
void sphere_ibsde_kernel_fb(
    const float* __restrict__ x0,  const float* __restrict__ dBt,
    const float* __restrict__ Dv,
    const float* __restrict__ pW1, const float* __restrict__ pb1,
    const float* __restrict__ pW2, const float* __restrict__ pb2,
    const float* __restrict__ pW3, const float* __restrict__ pb3,
    const float* __restrict__ gW1, const float* __restrict__ gb1,
    const float* __restrict__ gW2, const float* __restrict__ gb2,
    const float* __restrict__ gW3, const float* __restrict__ gb3,
    float* __restrict__ out)
{
    __shared__ float xsT[96 * SX];
    __shared__ float h1T[256 * SH];
    __shared__ float h2T[256 * SH];
    __shared__ float wbuf[16 * 256];
    __shared__ float sP[FNE], sRun[FNE], sRel[FNE];

    const int tid = threadIdx.x;
    const int b0 = blockIdx.x * FNE;

    #pragma unroll
    for (int i = 0; i < 6; ++i) {
        const int f = tid + i*256;
        const int e = f / 96, k = f - e*96;
        xsT[k*SX + e] = x0[(size_t)b0*96 + f];
    }

    layer256_fb(96,  pW1, pb1, xsT, SX, h1T, wbuf, tid);
    layer256_fb(256, pW2, pb2, h1T, SH, h2T, wbuf, tid);
    __syncthreads();
    {
        const int e = tid >> 4, tt = tid & 15;
        float s = 0.f;
        #pragma unroll
        for (int i = 0; i < 16; ++i) {
            const int k = tt + (i << 4);
            s += h2T[k*SH + e] * pW3[k];
        }
        #pragma unroll
        for (int m = 1; m <= 8; m <<= 1) s += __shfl_xor(s, m);
        if (tt == 0) { sP[e] = s + pb3[0]; sRun[e] = 1.0f; sRel[e] = 0.0f; }
    }

    const int ttc = tid & 15;
    const float s2d0 = sqrtf(2.0f * Dv[ttc]);
    const float s2d1 = sqrtf(2.0f * Dv[ttc + 16]);
    const float sqdt = sqrtf(0.01f);

    for (int t = 0; t < NSTEPS; ++t) {
        layer256_fb(96,  gW1 + (size_t)t*96*256,  gb1 + (size_t)t*256, xsT, SX, h1T, wbuf, tid);
        layer256_fb(256, gW2 + (size_t)t*256*256, gb2 + (size_t)t*256, h1T, SH, h2T, wbuf, tid);
        layer3_fb(gW3 + (size_t)t*256*96, gb3 + (size_t)t*96, h2T, wbuf, wbuf, tid);
        particles_step_fb(t, b0, dBt, s2d0, s2d1, sqdt, xsT, wbuf, sP, sRun, sRel, tid);
    }

    __syncthreads();
    {
        const int e = tid >> 4, tt = tid & 15;
        const int b = b0 + e;
        float s = 0.f;
        #pragma unroll
        for (int i = 0; i < 6; ++i) s += xsT[(tt*6 + i)*SX + e];
        #pragma unroll
        for (int m = 1; m <= 8; m <<= 1) s += __shfl_xor(s, m);
        if (tt == 0) {
            out[2*b] = sP[e];
            float pr = sRel[e];
            if (sRun[e] > 0.5f) pr = s / 96.0f;
            out[2*b + 1] = pr;
        }
    }
}

// =====================================================================
extern "C" void kernel_launch(void* const* d_in, const int* in_sizes, int n_in,
                              void* d_out, int out_size, void* d_ws, size_t ws_size,
                              hipStream_t stream)
{
    const float* x0  = (const float*)d_in[0];
    const float* dBt = (const float*)d_in[1];
    const float* Dv  = (const float*)d_in[2];
    const float* pW1 = (const float*)d_in[3];
    const float* pb1 = (const float*)d_in[4];
    const float* pW2 = (const float*)d_in[5];
    const float* pb2 = (const float*)d_in[6];
    const float* pW3 = (const float*)d_in[7];
    const float* pb3 = (const float*)d_in[8];
    const float* gW1 = (const float*)d_in[9];
    const float* gb1 = (const float*)d_in[10];
    const float* gW2 = (const float*)d_in[11];
    const float* gb2 = (const float*)d_in[12];
    const float* gW3 = (const float*)d_in[13];
    const float* gb3 = (const float*)d_in[14];
    float* out = (float*)d_out;

    // fragment-layout sizes in shorts
    const size_t A1 = (size_t)NSTEPS * 16 * 3 * 1024;
    const size_t A2 = (size_t)NSTEPS * 16 * 8 * 1024;
    const size_t A3 = (size_t)NSTEPS *  6 * 8 * 1024;
    const size_t P1 = (size_t)16 * 3 * 1024;
    const size_t P2 = (size_t)16 * 8 * 1024;
    const size_t total_elems = A1 + A2 + A3 + P1 + P2;

    if (ws_size >= total_elems * sizeof(short)) {
        short* p = (short*)d_ws;
        short* gW1f = p;            p += A1;
        short* gW2f = p;            p += A2;
        short* gW3f = p;            p += A3;
        short* pW1f = p;            p += P1;
        short* pW2f = p;            p += P2;

        // grids: one block per (t, kc, q)
        prep_frag_n256<<<dim3(NSTEPS*3*4), dim3(256), 0, stream>>>(gW1, gW1f, 96);
        prep_frag_n256<<<dim3(NSTEPS*8*4), dim3(256), 0, stream>>>(gW2, gW2f, 256);
        prep_frag_n96 <<<dim3(NSTEPS*8*4), dim3(128), 0, stream>>>(gW3, gW3f);
        prep_frag_n256<<<dim3(3*4),        dim3(256), 0, stream>>>(pW1, pW1f, 96);
        prep_frag_n256<<<dim3(8*4),        dim3(256), 0, stream>>>(pW2, pW2f, 256);

        sphere_mfma_kernel<<<dim3(BATCH / NE), dim3(1024), 0, stream>>>(
            x0, dBt, Dv,
            pW1f, pb1, pW2f, pb2, pW3, pb3,
            gW1f, gb1, gW2f, gb2, gW3f, gb3, out);
    } else {
        sphere_ibsde_kernel_fb<<<dim3(BATCH / FNE), dim3(256), 0, stream>>>(
            x0, dBt, Dv, pW1, pb1, pW2, pb2, pW3, pb3,
            gW1, gb1, gW2, gb2, gW3, gb3, out);
    }
}